// Round 14
// baseline (1225.045 us; speedup 1.0000x reference)
//
#include <hip/hip_runtime.h>

// VQ layer: N=262144 rows (D=256), K=1024 codes.
// out (FLOAT32): [z_q: N*D][loss_vq][loss_mean][indices(as float): N]
//
// Indices = numpy-f32 argmin of d = fl32( fl32(A_np + s_np,k) - fl32(2*M_k) ),
// tie -> lowest index. fp16-MFMA pass (keyed top-3) decides rows with top-2
// gap >= M1F; flagged rows resolved by exact np-emulation kernels.
// Round 14: BARRIER-FREE k_main. B-fragments are read directly from a linear
// L2-resident fp16 codebook image (512 KB) -- no LDS tiles, no per-tile
// barriers, no DMA convoy. Each wave is pure dataflow; compiler pipelines
// next-tile loads under current-tile MFMAs.

#define NROWS 262144
#define KCODES 1024
#define DDIM 256
#define ND ((size_t)NROWS * (size_t)DDIM)
#define M1F 6e-4f

typedef unsigned int uint;
typedef _Float16 f16x8 __attribute__((ext_vector_type(8)));
typedef float f32x4v __attribute__((ext_vector_type(4)));

// ---- IEEE-exact f32 ops: NON-volatile (schedulable, never contracted) ----
__device__ inline float fadd(float a, float b) {
    float d; asm("v_add_f32 %0, %1, %2" : "=v"(d) : "v"(a), "v"(b)); return d;
}
__device__ inline float fmul(float a, float b) {
    float d; asm("v_mul_f32 %0, %1, %2" : "=v"(d) : "v"(a), "v"(b)); return d;
}
__device__ inline float fsub(float a, float b) {
    float d; asm("v_sub_f32 %0, %1, %2" : "=v"(d) : "v"(a), "v"(b)); return d;
}
__device__ inline float ffma(float a, float b, float c) {
    float d; asm("v_fma_f32 %0, %1, %2, %3" : "=v"(d) : "v"(a), "v"(b), "v"(c)); return d;
}

// numpy pairwise sum of a[i]^2, n=256 (exact np order).
__device__ float np_sq_sum256(const float* __restrict__ a) {
    float tot[2];
    #pragma unroll 1
    for (int h = 0; h < 2; ++h) {
        const float* p = a + h * 128;
        float r[8];
        #pragma unroll
        for (int j = 0; j < 8; ++j) r[j] = fmul(p[j], p[j]);
        #pragma unroll 1
        for (int i = 8; i < 128; i += 8)
            #pragma unroll
            for (int j = 0; j < 8; ++j) r[j] = fadd(r[j], fmul(p[i + j], p[i + j]));
        tot[h] = fadd(fadd(fadd(r[0], r[1]), fadd(r[2], r[3])),
                      fadd(fadd(r[4], r[5]), fadd(r[6], r[7])));
    }
    return fadd(tot[0], tot[1]);
}

// BLAS-style f32 dot: single-accumulator serial FMA chain, ascending k.
__device__ float blas_dot256(const float* __restrict__ zr, const float* __restrict__ cr) {
    float dot = 0.f;
    #pragma unroll 4
    for (int d4 = 0; d4 < 64; ++d4) {
        float4 zz = *(const float4*)(zr + d4 * 4);
        float4 cc = *(const float4*)(cr + d4 * 4);
        dot = ffma(zz.x, cc.x, dot); dot = ffma(zz.y, cc.y, dot);
        dot = ffma(zz.z, cc.z, dot); dot = ffma(zz.w, cc.w, dot);
    }
    return dot;
}

// ---- k_prep: fused {cvt linear fp16 image (128 blk), codestats (4), colsum (16)} ----
__global__ void k_prep(const float* __restrict__ cb, char* __restrict__ cbh,
                       float* __restrict__ scp, float* __restrict__ mAcc) {
    int bx = blockIdx.x;
    if (bx < 128) {
        int g = bx * 256 + threadIdx.x;          // 0..32767 f16x8 groups
        const float* s = cb + (size_t)g * 8;
        float4 v0 = *(const float4*)s, v1 = *(const float4*)(s + 4);
        f16x8 h;
        h[0] = (_Float16)(v0.x * 1024.f); h[1] = (_Float16)(v0.y * 1024.f);
        h[2] = (_Float16)(v0.z * 1024.f); h[3] = (_Float16)(v0.w * 1024.f);
        h[4] = (_Float16)(v1.x * 1024.f); h[5] = (_Float16)(v1.y * 1024.f);
        h[6] = (_Float16)(v1.z * 1024.f); h[7] = (_Float16)(v1.w * 1024.f);
        *(f16x8*)(cbh + (size_t)g * 16) = h;     // linear: code*512 + d*2
    } else if (bx < 132) {
        int code = (bx - 128) * 256 + threadIdx.x;
        if (code < KCODES) scp[code] = np_sq_sum256(cb + (size_t)code * DDIM);
    } else {
        int d = threadIdx.x;
        int b = bx - 132;
        float s = 0.f;
        for (int i = 0; i < 64; ++i) s += cb[(size_t)(b * 64 + i) * DDIM + d];
        atomicAdd(&mAcc[d], s);
    }
}

// ---- k1c: finalize mean vector + ||m||^2 ----
__global__ void k_meanfin(const float* __restrict__ mAcc,
                          float* __restrict__ mvec, double* __restrict__ M2p) {
    __shared__ double red[256];
    int d = threadIdx.x;
    float m = mAcc[d] * (1.0f / 1024.0f);
    mvec[d] = m;
    red[d] = (double)m * (double)m;
    __syncthreads();
    for (int off = 128; off; off >>= 1) {
        if (d < off) red[d] += red[d + off];
        __syncthreads();
    }
    if (d == 0) *M2p = red[0];
}

// ---- k2: main MFMA pass — barrier-free, B direct from L2 ----
__launch_bounds__(256, 2)
__global__ void k_main(const float* __restrict__ z, const char* __restrict__ cbh,
                       const float* __restrict__ sc, const float* __restrict__ mvec,
                       float* __restrict__ out, uint* __restrict__ counts,
                       uint2* __restrict__ listTri, uint* __restrict__ listFull,
                       int capTri, int capFull,
                       double* __restrict__ lossA, double* __restrict__ lossB) {
    __shared__ float sc_lds[1024];
    __shared__ float statA[128], statZM[128];
    __shared__ float lred[2];

    const int tid = threadIdx.x;
    const int wave = tid >> 6;          // 0..3
    const int lane = tid & 63;
    const int l15 = lane & 15;
    const int lg = lane >> 4;
    const int blockRow = blockIdx.x * 128;

    if (tid < 2) lred[tid] = 0.f;
    for (int i = tid; i < 1024; i += 256) sc_lds[i] = sc[i];

    // --- z rows -> fp16 A-frags; per-row sum(z^2), z.m (losses) ---
    f16x8 za[2][8];
    #pragma unroll
    for (int m = 0; m < 2; ++m) {
        const float* zr = z + (size_t)(blockRow + wave * 32 + m * 16 + l15) * DDIM;
        float a2 = 0.f, zm = 0.f;
        #pragma unroll
        for (int kk = 0; kk < 8; ++kk) {
            int d0 = kk * 32 + lg * 8;
            float4 v0 = *(const float4*)(zr + d0);
            float4 v1 = *(const float4*)(zr + d0 + 4);
            float4 w0 = *(const float4*)(mvec + d0);
            float4 w1 = *(const float4*)(mvec + d0 + 4);
            a2 += v0.x * v0.x + v0.y * v0.y + v0.z * v0.z + v0.w * v0.w;
            a2 += v1.x * v1.x + v1.y * v1.y + v1.z * v1.z + v1.w * v1.w;
            zm += v0.x * w0.x + v0.y * w0.y + v0.z * w0.z + v0.w * w0.w;
            zm += v1.x * w1.x + v1.y * w1.y + v1.z * w1.z + v1.w * w1.w;
            f16x8 h;
            h[0] = (_Float16)v0.x; h[1] = (_Float16)v0.y;
            h[2] = (_Float16)v0.z; h[3] = (_Float16)v0.w;
            h[4] = (_Float16)v1.x; h[5] = (_Float16)v1.y;
            h[6] = (_Float16)v1.z; h[7] = (_Float16)v1.w;
            za[m][kk] = h;
        }
        a2 += __shfl_xor(a2, 16); a2 += __shfl_xor(a2, 32);
        zm += __shfl_xor(zm, 16); zm += __shfl_xor(zm, 32);
        if (lg == 0) {
            statA[wave * 32 + m * 16 + l15] = a2;
            statZM[wave * 32 + m * 16 + l15] = zm;
        }
    }
    __syncthreads();   // sc_lds + statA visible; ONLY barrier before epilogue

    float k1v[2][2][4], k2v[2][2][4], k3v[2][2][4];
    #pragma unroll
    for (int n = 0; n < 2; ++n)
        #pragma unroll
        for (int m = 0; m < 2; ++m)
            #pragma unroll
            for (int r = 0; r < 4; ++r) {
                k1v[n][m][r] = 3e38f; k2v[n][m][r] = 3e38f; k3v[n][m][r] = 3e38f;
            }

    // --- barrier-free main loop: 32 tiles x 32 codes ---
    // lane's B-frag address: code*512 + kk*64 + lg*16, code = t*32 + n*16 + l15
    const char* bbase = cbh + (size_t)l15 * 512 + (size_t)lg * 16;
    #pragma unroll 1
    for (int t = 0; t < 32; ++t) {
        const char* tb = bbase + (size_t)t * 16384;
        f32x4v acc[2][2];
        #pragma unroll
        for (int m = 0; m < 2; ++m)
            #pragma unroll
            for (int n = 0; n < 2; ++n) acc[m][n] = (f32x4v){0.f, 0.f, 0.f, 0.f};
        #pragma unroll
        for (int kk = 0; kk < 8; ++kk) {
            f16x8 b0 = *(const f16x8*)(tb + kk * 64);
            f16x8 b1 = *(const f16x8*)(tb + 8192 + kk * 64);
            acc[0][0] = __builtin_amdgcn_mfma_f32_16x16x32_f16(za[0][kk], b0, acc[0][0], 0, 0, 0);
            acc[1][0] = __builtin_amdgcn_mfma_f32_16x16x32_f16(za[1][kk], b0, acc[1][0], 0, 0, 0);
            acc[0][1] = __builtin_amdgcn_mfma_f32_16x16x32_f16(za[0][kk], b1, acc[0][1], 0, 0, 0);
            acc[1][1] = __builtin_amdgcn_mfma_f32_16x16x32_f16(za[1][kk], b1, acc[1][1], 0, 0, 0);
        }
        int tbase = t * 32;
        #pragma unroll
        for (int n = 0; n < 2; ++n) {
            int codev = tbase + n * 16 + l15;
            float scv = sc_lds[codev];
            #pragma unroll
            for (int m = 0; m < 2; ++m)
                #pragma unroll
                for (int r = 0; r < 4; ++r) {
                    float s = fmaf(acc[m][n][r], -0.001953125f, scv);
                    uint kb = (__float_as_uint(s) & 0xFFFFFC00u) | (uint)codev;
                    float k = __uint_as_float(kb);
                    float o1 = k1v[n][m][r], o2 = k2v[n][m][r];
                    k3v[n][m][r] = __builtin_amdgcn_fmed3f(o2, k3v[n][m][r], k);
                    k2v[n][m][r] = __builtin_amdgcn_fmed3f(o1, o2, k);
                    k1v[n][m][r] = fminf(o1, k);
                }
        }
    }

    // --- fold n=0/n=1 key banks, then cross-lane top-3 merge + writeback ---
    float lA = 0.f, lB = 0.f;
    #pragma unroll
    for (int m = 0; m < 2; ++m)
        #pragma unroll
        for (int r = 0; r < 4; ++r) {
            float x1 = k1v[0][m][r], x2 = k2v[0][m][r], x3 = k3v[0][m][r];
            float y1 = k1v[1][m][r], y2 = k2v[1][m][r], y3 = k3v[1][m][r];
            float mx = fmaxf(x1, y1);
            float a3 = fminf(fminf(__builtin_amdgcn_fmed3f(x2, y2, mx), x3), y3);
            float a2 = fminf(fminf(mx, x2), y2);
            float a1 = fminf(x1, y1);
            #pragma unroll
            for (int mk = 1; mk <= 8; mk <<= 1) {
                float b1 = __shfl_xor(a1, mk);
                float b2 = __shfl_xor(a2, mk);
                float b3 = __shfl_xor(a3, mk);
                float mx2 = fmaxf(a1, b1);
                float n3 = fminf(fminf(__builtin_amdgcn_fmed3f(a2, b2, mx2), a3), b3);
                float n2 = fminf(fminf(mx2, a2), b2);
                a1 = fminf(a1, b1); a2 = n2; a3 = n3;
            }
            if (l15 == 0) {
                int rowL = wave * 32 + m * 16 + lg * 4 + r;
                int row = blockRow + rowL;
                int i1 = (int)(__float_as_uint(a1) & 1023u);
                int i2 = (int)(__float_as_uint(a2) & 1023u);
                int i3 = (int)(__float_as_uint(a3) & 1023u);
                int flag = (a3 - a1 < M1F) ? 2 : ((a2 - a1 < M1F) ? 1 : 0);
                float slotval = (float)i1;
                if (flag == 2) {
                    uint p = atomicAdd(&counts[1], 1u);
                    if (p < (uint)capFull) listFull[p] = (uint)row;
                    else slotval = (float)(i1 | (1 << 20));
                } else if (flag == 1) {
                    uint p = atomicAdd(&counts[0], 1u);
                    if (p < (uint)capTri)
                        listTri[p] = make_uint2((uint)row, (uint)(i1 | (i2 << 10) | (i3 << 20)));
                    else slotval = (float)(i1 | (1 << 20));
                }
                out[ND + 2 + (size_t)row] = slotval;
                lA += statA[rowL] + a1;
                lB += statA[rowL] - 2.f * statZM[rowL];
            }
        }
    if (l15 == 0) { atomicAdd(&lred[0], lA); atomicAdd(&lred[1], lB); }
    __syncthreads();
    if (tid == 0) {
        atomicAdd(lossA, (double)lred[0]);
        atomicAdd(lossB, (double)lred[1]);
    }
}

// ---- k_gather: standalone high-occupancy z_q gather (128 rows/block) ----
__global__ void k_gather(const float* __restrict__ cb, float* __restrict__ out) {
    __shared__ int idx[128];
    const int tid = threadIdx.x;
    const int blockRow = blockIdx.x * 128;
    if (tid < 128) idx[tid] = ((int)out[ND + 2 + (size_t)(blockRow + tid)]) & 1023;
    __syncthreads();
    float4* out4 = (float4*)out;
    const float4* cb4 = (const float4*)cb;
    #pragma unroll 4
    for (int i = 0; i < 32; ++i) {
        int q = i * 256 + tid;              // 128 rows x 64 float4
        int rowL = q >> 6, ch = q & 63;
        int code = idx[rowL];
        out4[(size_t)(blockRow + rowL) * 64 + ch] = cb4[(size_t)code * 64 + ch];
    }
}

// ---- k3a: triple refine — one WAVE per flagged row, coalesced loads ----
__launch_bounds__(256)
__global__ void k_refine_tri(const float* __restrict__ z, const float* __restrict__ cb,
                             const float* __restrict__ scp,
                             const uint* __restrict__ counts,
                             const uint2* __restrict__ listTri, int capTri,
                             float* __restrict__ out) {
    __shared__ float B[4][4][256];
    const int wv = threadIdx.x >> 6;
    const int lane = threadIdx.x & 63;
    uint n = counts[0];
    if (n > (uint)capTri) n = (uint)capTri;
    uint nw = gridDim.x * 4;
    for (uint it = blockIdx.x * 4 + wv; it < n; it += nw) {
        uint2 e = listTri[it];
        int row = (int)e.x;
        int i1 = (int)(e.y & 1023), i2 = (int)((e.y >> 10) & 1023), i3 = (int)((e.y >> 20) & 1023);
        *(float4*)&B[wv][0][lane * 4] = *(const float4*)(z + (size_t)row * DDIM + lane * 4);
        *(float4*)&B[wv][1][lane * 4] = *(const float4*)(cb + (size_t)i1 * DDIM + lane * 4);
        *(float4*)&B[wv][2][lane * 4] = *(const float4*)(cb + (size_t)i2 * DDIM + lane * 4);
        *(float4*)&B[wv][3][lane * 4] = *(const float4*)(cb + (size_t)i3 * DDIM + lane * 4);
        asm volatile("s_waitcnt vmcnt(0) lgkmcnt(0)" ::: "memory");
        __builtin_amdgcn_sched_barrier(0);
        float A = np_sq_sum256(B[wv][0]);
        float dA = 0.f, dB = 0.f, dC = 0.f;
        #pragma unroll 4
        for (int d4 = 0; d4 < 64; ++d4) {
            float4 zz = *(const float4*)&B[wv][0][d4 * 4];
            float4 ca = *(const float4*)&B[wv][1][d4 * 4];
            float4 cc = *(const float4*)&B[wv][2][d4 * 4];
            float4 cd = *(const float4*)&B[wv][3][d4 * 4];
            dA = ffma(zz.x, ca.x, dA); dA = ffma(zz.y, ca.y, dA);
            dA = ffma(zz.z, ca.z, dA); dA = ffma(zz.w, ca.w, dA);
            dB = ffma(zz.x, cc.x, dB); dB = ffma(zz.y, cc.y, dB);
            dB = ffma(zz.z, cc.z, dB); dB = ffma(zz.w, cc.w, dB);
            dC = ffma(zz.x, cd.x, dC); dC = ffma(zz.y, cd.y, dC);
            dC = ffma(zz.z, cd.z, dC); dC = ffma(zz.w, cd.w, dC);
        }
        float d1 = fsub(fadd(A, scp[i1]), fmul(2.f, dA));
        float d2 = fsub(fadd(A, scp[i2]), fmul(2.f, dB));
        float d3 = fsub(fadd(A, scp[i3]), fmul(2.f, dC));
        int win = i1; float bd = d1;
        if (d2 < bd || (d2 == bd && i2 < win)) { bd = d2; win = i2; }
        if (d3 < bd || (d3 == bd && i3 < win)) { bd = d3; win = i3; }
        if (win != i1) {
            if (lane == 0) out[ND + 2 + (size_t)row] = (float)win;
            *(float4*)(out + (size_t)row * DDIM + lane * 4) =
                *(const float4*)(cb + (size_t)win * DDIM + lane * 4);
        }
    }
}

// ---- k3b: full np rescan — one block per flagged row ----
__launch_bounds__(256, 2)
__global__ void k_refine_full(const float* __restrict__ z, const float* __restrict__ cb,
                              const float* __restrict__ scp,
                              const uint* __restrict__ counts,
                              const uint* __restrict__ listFull, int capFull,
                              float* __restrict__ out) {
    __shared__ float zrow[256];
    __shared__ float avs[256];
    __shared__ int ais[256];
    __shared__ int winsh;

    uint n = counts[1];
    if (n > (uint)capFull) n = (uint)capFull;
    const int tid = threadIdx.x;

    for (uint j = blockIdx.x; j < n; j += gridDim.x) {
        int row = (int)listFull[j];
        __syncthreads();
        if (tid < 64)
            *(float4*)&zrow[tid * 4] = *(const float4*)(z + (size_t)row * DDIM + tid * 4);
        __syncthreads();

        float A = np_sq_sum256(zrow);

        float d0 = 0.f, d1 = 0.f, d2 = 0.f, d3 = 0.f;
        const float* c0 = cb + (size_t)(tid + 0) * DDIM;
        const float* c1 = cb + (size_t)(tid + 256) * DDIM;
        const float* c2 = cb + (size_t)(tid + 512) * DDIM;
        const float* c3 = cb + (size_t)(tid + 768) * DDIM;
        #pragma unroll 4
        for (int q = 0; q < 64; ++q) {
            float4 zz = *(const float4*)&zrow[q * 4];
            float4 a = *(const float4*)(c0 + q * 4);
            float4 b = *(const float4*)(c1 + q * 4);
            float4 c = *(const float4*)(c2 + q * 4);
            float4 d = *(const float4*)(c3 + q * 4);
            d0 = ffma(zz.x, a.x, d0); d0 = ffma(zz.y, a.y, d0);
            d0 = ffma(zz.z, a.z, d0); d0 = ffma(zz.w, a.w, d0);
            d1 = ffma(zz.x, b.x, d1); d1 = ffma(zz.y, b.y, d1);
            d1 = ffma(zz.z, b.z, d1); d1 = ffma(zz.w, b.w, d1);
            d2 = ffma(zz.x, c.x, d2); d2 = ffma(zz.y, c.y, d2);
            d2 = ffma(zz.z, c.z, d2); d2 = ffma(zz.w, c.w, d2);
            d3 = ffma(zz.x, d.x, d3); d3 = ffma(zz.y, d.y, d3);
            d3 = ffma(zz.z, d.z, d3); d3 = ffma(zz.w, d.w, d3);
        }
        float best = 1e30f; int bi = 0x7fffffff;
        float dd[4] = {d0, d1, d2, d3};
        #pragma unroll
        for (int kk = 0; kk < 4; ++kk) {
            int code = tid + kk * 256;
            float dist = fsub(fadd(A, scp[code]), fmul(2.f, dd[kk]));
            if (dist < best || (dist == best && code < bi)) { best = dist; bi = code; }
        }
        avs[tid] = best; ais[tid] = bi;
        __syncthreads();
        for (int off = 128; off; off >>= 1) {
            if (tid < off) {
                float o = avs[tid + off]; int oi = ais[tid + off];
                if (o < avs[tid] || (o == avs[tid] && oi < ais[tid])) {
                    avs[tid] = o; ais[tid] = oi;
                }
            }
            __syncthreads();
        }
        if (tid == 0) {
            winsh = ais[0];
            out[ND + 2 + (size_t)row] = (float)ais[0];
        }
        __syncthreads();
        int win = winsh;
        out[(size_t)row * DDIM + tid] = cb[(size_t)win * DDIM + tid];
    }
}

// ---- k3c: sweep for worklist-overflow rows (normally a pure read pass) ----
__global__ void k_sweep(const float* __restrict__ z, const float* __restrict__ cb,
                        const float* __restrict__ scp, float* __restrict__ out) {
    int row = blockIdx.x * 256 + threadIdx.x;
    float v = out[ND + 2 + (size_t)row];
    if (v < 1048576.f) return;
    int enc = (int)v;
    int i1 = enc & 1023;
    const float* zr = z + (size_t)row * DDIM;
    float A = np_sq_sum256(zr);
    float best = 1e30f; int win = 0x7fffffff;
    for (int code = 0; code < KCODES; ++code) {
        float dot = blas_dot256(zr, cb + (size_t)code * DDIM);
        float dist = fsub(fadd(A, scp[code]), fmul(2.f, dot));
        if (dist < best) { best = dist; win = code; }
    }
    out[ND + 2 + (size_t)row] = (float)win;
    if (win != i1) {
        const float4* cw = (const float4*)(cb + (size_t)win * DDIM);
        float4* ow = (float4*)(out + (size_t)row * DDIM);
        for (int c = 0; c < 64; ++c) ow[c] = cw[c];
    }
}

// ---- k4: finalize scalar losses ----
__global__ void k_final(const double* __restrict__ lossA, const double* __restrict__ lossB,
                        const double* __restrict__ M2p, float* __restrict__ out) {
    if (threadIdx.x == 0) {
        double nd = (double)ND;
        out[ND] = (float)(*lossA / nd);
        out[ND + 1] = (float)((*lossB + (double)NROWS * (*M2p)) / nd);
    }
}

extern "C" void kernel_launch(void* const* d_in, const int* in_sizes, int n_in,
                              void* d_out, int out_size, void* d_ws, size_t ws_size,
                              hipStream_t stream) {
    const float* z = (const float*)d_in[0];
    const float* cb = (const float*)d_in[1];
    float* out = (float*)d_out;

    // ws: [0 lossA][8 lossB][16 M2p][24 counts(2)][32 mAcc 1KB]
    //     [2048 mvec][4096 scp 4KB][8192 cbh 512KB][532480 listFull | listTri]
    double* lossA = (double*)d_ws;
    double* lossB = lossA + 1;
    double* M2p   = lossA + 2;
    uint*   counts = (uint*)((char*)d_ws + 24);
    float*  mAcc  = (float*)((char*)d_ws + 32);
    float*  mvec  = (float*)((char*)d_ws + 2048);
    float*  scp   = (float*)((char*)d_ws + 4096);
    char*   cbh   = (char*)d_ws + 8192;

    size_t base = 8192 + 524288;
    size_t avail = ws_size > base ? ws_size - base : 0;
    int capFull = (int)(avail / 24);
    if (capFull > 32768) capFull = 32768;
    size_t fullBytes = ((size_t)capFull * 4 + 7) & ~(size_t)7;
    size_t availTri = avail > fullBytes ? avail - fullBytes : 0;
    int capTri = (int)(availTri / 8);
    if (capTri > 131072) capTri = 131072;

    uint*  listFull = (uint*)((char*)d_ws + base);
    uint2* listTri  = (uint2*)((char*)d_ws + base + fullBytes);

    hipMemsetAsync(d_ws, 0, 1056, stream);
    k_prep<<<148, 256, 0, stream>>>(cb, cbh, scp, mAcc);
    k_meanfin<<<1, 256, 0, stream>>>(mAcc, mvec, M2p);
    k_main<<<NROWS / 128, 256, 0, stream>>>(z, cbh, scp, mvec, out,
                                            counts, listTri, listFull,
                                            capTri, capFull, lossA, lossB);
    k_gather<<<NROWS / 128, 256, 0, stream>>>(cb, out);
    k_refine_tri<<<512, 256, 0, stream>>>(z, cb, scp, counts, listTri, capTri, out);
    k_refine_full<<<1024, 256, 0, stream>>>(z, cb, scp, counts, listFull, capFull, out);
    k_sweep<<<NROWS / 256, 256, 0, stream>>>(z, cb, scp, out);
    k_final<<<1, 64, 0, stream>>>(lossA, lossB, M2p, out);
}

// Round 15
// 1195.838 us; speedup vs baseline: 1.0244x; 1.0244x over previous
//
#include <hip/hip_runtime.h>

// VQ layer: N=262144 rows (D=256), K=1024 codes.
// out (FLOAT32): [z_q: N*D][loss_vq][loss_mean][indices(as float): N]
//
// Indices = numpy-f32 argmin of d = fl32( fl32(A_np + s_np,k) - fl32(2*M_k) ),
// tie -> lowest index. fp16-MFMA pass (keyed top-3) decides rows with top-2
// gap >= M1F; flagged rows resolved by exact np-emulation kernels (index-only).
// Round 15: 32-code tiles (2x16KB, ~38KB LDS -> 4 blocks/CU) with NO
// launch_bounds (no VGPR cap -> no spill; r12/r13's regression isolated to
// the spill). r11's counted-vmcnt schedule. z_q gathered once, LAST.

#define NROWS 262144
#define KCODES 1024
#define DDIM 256
#define ND ((size_t)NROWS * (size_t)DDIM)
#define M1F 6e-4f

typedef unsigned int uint;
typedef _Float16 f16x8 __attribute__((ext_vector_type(8)));
typedef float f32x4v __attribute__((ext_vector_type(4)));

// ---- IEEE-exact f32 ops: NON-volatile (schedulable, never contracted) ----
__device__ inline float fadd(float a, float b) {
    float d; asm("v_add_f32 %0, %1, %2" : "=v"(d) : "v"(a), "v"(b)); return d;
}
__device__ inline float fmul(float a, float b) {
    float d; asm("v_mul_f32 %0, %1, %2" : "=v"(d) : "v"(a), "v"(b)); return d;
}
__device__ inline float fsub(float a, float b) {
    float d; asm("v_sub_f32 %0, %1, %2" : "=v"(d) : "v"(a), "v"(b)); return d;
}
__device__ inline float ffma(float a, float b, float c) {
    float d; asm("v_fma_f32 %0, %1, %2, %3" : "=v"(d) : "v"(a), "v"(b), "v"(c)); return d;
}

// numpy pairwise sum of a[i]^2, n=256 (exact np order).
__device__ float np_sq_sum256(const float* __restrict__ a) {
    float tot[2];
    #pragma unroll 1
    for (int h = 0; h < 2; ++h) {
        const float* p = a + h * 128;
        float r[8];
        #pragma unroll
        for (int j = 0; j < 8; ++j) r[j] = fmul(p[j], p[j]);
        #pragma unroll 1
        for (int i = 8; i < 128; i += 8)
            #pragma unroll
            for (int j = 0; j < 8; ++j) r[j] = fadd(r[j], fmul(p[i + j], p[i + j]));
        tot[h] = fadd(fadd(fadd(r[0], r[1]), fadd(r[2], r[3])),
                      fadd(fadd(r[4], r[5]), fadd(r[6], r[7])));
    }
    return fadd(tot[0], tot[1]);
}

// BLAS-style f32 dot: single-accumulator serial FMA chain, ascending k.
__device__ float blas_dot256(const float* __restrict__ zr, const float* __restrict__ cr) {
    float dot = 0.f;
    #pragma unroll 4
    for (int d4 = 0; d4 < 64; ++d4) {
        float4 zz = *(const float4*)(zr + d4 * 4);
        float4 cc = *(const float4*)(cr + d4 * 4);
        dot = ffma(zz.x, cc.x, dot); dot = ffma(zz.y, cc.y, dot);
        dot = ffma(zz.z, cc.z, dot); dot = ffma(zz.w, cc.w, dot);
    }
    return dot;
}

// ---- k_prep: fused {cvt 32-code swizzled tiles (128 blk), codestats (4), colsum (16)} ----
__global__ void k_prep(const float* __restrict__ cb, char* __restrict__ cbh,
                       float* __restrict__ scp, float* __restrict__ mAcc) {
    int bx = blockIdx.x;
    if (bx < 128) {
        int g = bx * 256 + threadIdx.x;          // 0..32767 f16x8 groups
        int t = g >> 10, c = (g >> 5) & 31, j = g & 31;
        const float* s = cb + (size_t)(t * 32 + c) * DDIM + j * 8;
        float4 v0 = *(const float4*)s, v1 = *(const float4*)(s + 4);
        f16x8 h;
        h[0] = (_Float16)(v0.x * 1024.f); h[1] = (_Float16)(v0.y * 1024.f);
        h[2] = (_Float16)(v0.z * 1024.f); h[3] = (_Float16)(v0.w * 1024.f);
        h[4] = (_Float16)(v1.x * 1024.f); h[5] = (_Float16)(v1.y * 1024.f);
        h[6] = (_Float16)(v1.z * 1024.f); h[7] = (_Float16)(v1.w * 1024.f);
        uint byte = (uint)(c * 512 + j * 16) ^ (uint)((c & 7) << 4);
        *(f16x8*)(cbh + (size_t)t * 16384 + byte) = h;
    } else if (bx < 132) {
        int code = (bx - 128) * 256 + threadIdx.x;
        if (code < KCODES) scp[code] = np_sq_sum256(cb + (size_t)code * DDIM);
    } else {
        int d = threadIdx.x;
        int b = bx - 132;
        float s = 0.f;
        for (int i = 0; i < 64; ++i) s += cb[(size_t)(b * 64 + i) * DDIM + d];
        atomicAdd(&mAcc[d], s);
    }
}

// ---- k1c: finalize mean vector + ||m||^2 ----
__global__ void k_meanfin(const float* __restrict__ mAcc,
                          float* __restrict__ mvec, double* __restrict__ M2p) {
    __shared__ double red[256];
    int d = threadIdx.x;
    float m = mAcc[d] * (1.0f / 1024.0f);
    mvec[d] = m;
    red[d] = (double)m * (double)m;
    __syncthreads();
    for (int off = 128; off; off >>= 1) {
        if (d < off) red[d] += red[d + off];
        __syncthreads();
    }
    if (d == 0) *M2p = red[0];
}

#define GLOAD_LDS16(g, l) \
    __builtin_amdgcn_global_load_lds( \
        (const __attribute__((address_space(1))) void*)(g), \
        (__attribute__((address_space(3))) void*)(l), 16, 0, 0)

// ---- k2: main MFMA pass (256 thr, 128 rows, 32-code tiles, NO reg cap) ----
__global__ void k_main(const float* __restrict__ z, const char* __restrict__ cbh,
                       const float* __restrict__ sc, const float* __restrict__ mvec,
                       float* __restrict__ out, uint* __restrict__ counts,
                       uint2* __restrict__ listTri, uint* __restrict__ listFull,
                       int capTri, int capFull,
                       double* __restrict__ lossA, double* __restrict__ lossB) {
    __shared__ char tiles[2][16384] __attribute__((aligned(16)));
    __shared__ float sc_lds[1024];
    __shared__ float statA[128], statZM[128];
    __shared__ float lred[2];

    const int tid = threadIdx.x;
    const int wave = tid >> 6;          // 0..3
    const int lane = tid & 63;
    const int l15 = lane & 15;
    const int lg = lane >> 4;
    const int blockRow = blockIdx.x * 128;

    if (tid < 2) lred[tid] = 0.f;
    for (int i = tid; i < 1024; i += 256) sc_lds[i] = sc[i];

    // --- z rows -> fp16 A-frags; per-row sum(z^2), z.m (losses) ---
    f16x8 za[2][8];
    #pragma unroll
    for (int m = 0; m < 2; ++m) {
        const float* zr = z + (size_t)(blockRow + wave * 32 + m * 16 + l15) * DDIM;
        float a2 = 0.f, zm = 0.f;
        #pragma unroll
        for (int kk = 0; kk < 8; ++kk) {
            int d0 = kk * 32 + lg * 8;
            float4 v0 = *(const float4*)(zr + d0);
            float4 v1 = *(const float4*)(zr + d0 + 4);
            float4 w0 = *(const float4*)(mvec + d0);
            float4 w1 = *(const float4*)(mvec + d0 + 4);
            a2 += v0.x * v0.x + v0.y * v0.y + v0.z * v0.z + v0.w * v0.w;
            a2 += v1.x * v1.x + v1.y * v1.y + v1.z * v1.z + v1.w * v1.w;
            zm += v0.x * w0.x + v0.y * w0.y + v0.z * w0.z + v0.w * w0.w;
            zm += v1.x * w1.x + v1.y * w1.y + v1.z * w1.z + v1.w * w1.w;
            f16x8 h;
            h[0] = (_Float16)v0.x; h[1] = (_Float16)v0.y;
            h[2] = (_Float16)v0.z; h[3] = (_Float16)v0.w;
            h[4] = (_Float16)v1.x; h[5] = (_Float16)v1.y;
            h[6] = (_Float16)v1.z; h[7] = (_Float16)v1.w;
            za[m][kk] = h;
        }
        a2 += __shfl_xor(a2, 16); a2 += __shfl_xor(a2, 32);
        zm += __shfl_xor(zm, 16); zm += __shfl_xor(zm, 32);
        if (lg == 0) {
            statA[wave * 32 + m * 16 + l15] = a2;
            statZM[wave * 32 + m * 16 + l15] = zm;
        }
    }
    __syncthreads();   // drains all prior vm loads -> vmcnt bookkeeping exact

    float k1v[2][2][4], k2v[2][2][4], k3v[2][2][4];
    #pragma unroll
    for (int n = 0; n < 2; ++n)
        #pragma unroll
        for (int m = 0; m < 2; ++m)
            #pragma unroll
            for (int r = 0; r < 4; ++r) {
                k1v[n][m][r] = 3e38f; k2v[n][m][r] = 3e38f; k3v[n][m][r] = 3e38f;
            }

    // DMA stage: 4 x 16B per thread per tile (4 waves x 4KB = 16KB)
    const char* gsrc0 = cbh + (size_t)wave * 4096 + (size_t)lane * 16;
    #define STAGE(T, BUF) { \
        const char* g_ = gsrc0 + (size_t)(T) * 16384; \
        char* l_ = &tiles[BUF][wave * 4096]; \
        _Pragma("unroll") \
        for (int i_ = 0; i_ < 4; ++i_) GLOAD_LDS16(g_ + i_ * 1024, l_ + i_ * 1024); \
    }

    #define COMPUTE(T, BUF) { \
        f32x4v acc[2][2]; \
        _Pragma("unroll") \
        for (int m = 0; m < 2; ++m) \
            _Pragma("unroll") \
            for (int n = 0; n < 2; ++n) acc[m][n] = (f32x4v){0.f, 0.f, 0.f, 0.f}; \
        const char* tb = &tiles[BUF][0]; \
        _Pragma("unroll") \
        for (int kk = 0; kk < 8; ++kk) { \
            _Pragma("unroll") \
            for (int n = 0; n < 2; ++n) { \
                int lcode = n * 16 + l15; \
                uint byte = (uint)(lcode * 512 + kk * 64 + lg * 16) ^ (uint)((lcode & 7) << 4); \
                f16x8 b = *(const f16x8*)(tb + byte); \
                acc[0][n] = __builtin_amdgcn_mfma_f32_16x16x32_f16(za[0][kk], b, acc[0][n], 0, 0, 0); \
                acc[1][n] = __builtin_amdgcn_mfma_f32_16x16x32_f16(za[1][kk], b, acc[1][n], 0, 0, 0); \
            } \
        } \
        int tbase = (T) * 32; \
        _Pragma("unroll") \
        for (int n = 0; n < 2; ++n) { \
            int codev = tbase + n * 16 + l15; \
            float scv = sc_lds[codev]; \
            _Pragma("unroll") \
            for (int m = 0; m < 2; ++m) \
                _Pragma("unroll") \
                for (int r = 0; r < 4; ++r) { \
                    float s = fmaf(acc[m][n][r], -0.001953125f, scv); \
                    uint kb = (__float_as_uint(s) & 0xFFFFFC00u) | (uint)codev; \
                    float k = __uint_as_float(kb); \
                    float o1 = k1v[n][m][r], o2 = k2v[n][m][r]; \
                    k3v[n][m][r] = __builtin_amdgcn_fmed3f(o2, k3v[n][m][r], k); \
                    k2v[n][m][r] = __builtin_amdgcn_fmed3f(o1, o2, k); \
                    k1v[n][m][r] = fminf(o1, k); \
                } \
        } \
    }

    STAGE(0, 0);
    #pragma unroll 1
    for (int t = 0; t < 31; ++t) {
        STAGE(t + 1, (t + 1) & 1);
        asm volatile("s_waitcnt vmcnt(4)" ::: "memory");
        __builtin_amdgcn_s_barrier();
        __builtin_amdgcn_sched_barrier(0);
        COMPUTE(t, t & 1);
        __builtin_amdgcn_sched_barrier(0);
        __builtin_amdgcn_s_barrier();
    }
    asm volatile("s_waitcnt vmcnt(0)" ::: "memory");
    __builtin_amdgcn_s_barrier();
    __builtin_amdgcn_sched_barrier(0);
    COMPUTE(31, 1);

    // --- fold n=0/n=1 key banks, then cross-lane top-3 merge + writeback ---
    float lA = 0.f, lB = 0.f;
    #pragma unroll
    for (int m = 0; m < 2; ++m)
        #pragma unroll
        for (int r = 0; r < 4; ++r) {
            float x1 = k1v[0][m][r], x2 = k2v[0][m][r], x3 = k3v[0][m][r];
            float y1 = k1v[1][m][r], y2 = k2v[1][m][r], y3 = k3v[1][m][r];
            float mx = fmaxf(x1, y1);
            float a3 = fminf(fminf(__builtin_amdgcn_fmed3f(x2, y2, mx), x3), y3);
            float a2 = fminf(fminf(mx, x2), y2);
            float a1 = fminf(x1, y1);
            #pragma unroll
            for (int mk = 1; mk <= 8; mk <<= 1) {
                float b1 = __shfl_xor(a1, mk);
                float b2 = __shfl_xor(a2, mk);
                float b3 = __shfl_xor(a3, mk);
                float mx2 = fmaxf(a1, b1);
                float n3 = fminf(fminf(__builtin_amdgcn_fmed3f(a2, b2, mx2), a3), b3);
                float n2 = fminf(fminf(mx2, a2), b2);
                a1 = fminf(a1, b1); a2 = n2; a3 = n3;
            }
            if (l15 == 0) {
                int rowL = wave * 32 + m * 16 + lg * 4 + r;
                int row = blockRow + rowL;
                int i1 = (int)(__float_as_uint(a1) & 1023u);
                int i2 = (int)(__float_as_uint(a2) & 1023u);
                int i3 = (int)(__float_as_uint(a3) & 1023u);
                int flag = (a3 - a1 < M1F) ? 2 : ((a2 - a1 < M1F) ? 1 : 0);
                float slotval = (float)i1;
                if (flag == 2) {
                    uint p = atomicAdd(&counts[1], 1u);
                    if (p < (uint)capFull) listFull[p] = (uint)row;
                    else slotval = (float)(i1 | (1 << 20));
                } else if (flag == 1) {
                    uint p = atomicAdd(&counts[0], 1u);
                    if (p < (uint)capTri)
                        listTri[p] = make_uint2((uint)row, (uint)(i1 | (i2 << 10) | (i3 << 20)));
                    else slotval = (float)(i1 | (1 << 20));
                }
                out[ND + 2 + (size_t)row] = slotval;
                lA += statA[rowL] + a1;
                lB += statA[rowL] - 2.f * statZM[rowL];
            }
        }
    if (l15 == 0) { atomicAdd(&lred[0], lA); atomicAdd(&lred[1], lB); }
    __syncthreads();
    if (tid == 0) {
        atomicAdd(lossA, (double)lred[0]);
        atomicAdd(lossB, (double)lred[1]);
    }
}

// ---- k3a: triple refine — one WAVE per flagged row, INDEX-ONLY write ----
__launch_bounds__(256)
__global__ void k_refine_tri(const float* __restrict__ z, const float* __restrict__ cb,
                             const float* __restrict__ scp,
                             const uint* __restrict__ counts,
                             const uint2* __restrict__ listTri, int capTri,
                             float* __restrict__ out) {
    __shared__ float B[4][4][256];
    const int wv = threadIdx.x >> 6;
    const int lane = threadIdx.x & 63;
    uint n = counts[0];
    if (n > (uint)capTri) n = (uint)capTri;
    uint nw = gridDim.x * 4;
    for (uint it = blockIdx.x * 4 + wv; it < n; it += nw) {
        uint2 e = listTri[it];
        int row = (int)e.x;
        int i1 = (int)(e.y & 1023), i2 = (int)((e.y >> 10) & 1023), i3 = (int)((e.y >> 20) & 1023);
        *(float4*)&B[wv][0][lane * 4] = *(const float4*)(z + (size_t)row * DDIM + lane * 4);
        *(float4*)&B[wv][1][lane * 4] = *(const float4*)(cb + (size_t)i1 * DDIM + lane * 4);
        *(float4*)&B[wv][2][lane * 4] = *(const float4*)(cb + (size_t)i2 * DDIM + lane * 4);
        *(float4*)&B[wv][3][lane * 4] = *(const float4*)(cb + (size_t)i3 * DDIM + lane * 4);
        asm volatile("s_waitcnt vmcnt(0) lgkmcnt(0)" ::: "memory");
        __builtin_amdgcn_sched_barrier(0);
        float A = np_sq_sum256(B[wv][0]);
        float dA = 0.f, dB = 0.f, dC = 0.f;
        #pragma unroll 4
        for (int d4 = 0; d4 < 64; ++d4) {
            float4 zz = *(const float4*)&B[wv][0][d4 * 4];
            float4 ca = *(const float4*)&B[wv][1][d4 * 4];
            float4 cc = *(const float4*)&B[wv][2][d4 * 4];
            float4 cd = *(const float4*)&B[wv][3][d4 * 4];
            dA = ffma(zz.x, ca.x, dA); dA = ffma(zz.y, ca.y, dA);
            dA = ffma(zz.z, ca.z, dA); dA = ffma(zz.w, ca.w, dA);
            dB = ffma(zz.x, cc.x, dB); dB = ffma(zz.y, cc.y, dB);
            dB = ffma(zz.z, cc.z, dB); dB = ffma(zz.w, cc.w, dB);
            dC = ffma(zz.x, cd.x, dC); dC = ffma(zz.y, cd.y, dC);
            dC = ffma(zz.z, cd.z, dC); dC = ffma(zz.w, cd.w, dC);
        }
        float d1 = fsub(fadd(A, scp[i1]), fmul(2.f, dA));
        float d2 = fsub(fadd(A, scp[i2]), fmul(2.f, dB));
        float d3 = fsub(fadd(A, scp[i3]), fmul(2.f, dC));
        int win = i1; float bd = d1;
        if (d2 < bd || (d2 == bd && i2 < win)) { bd = d2; win = i2; }
        if (d3 < bd || (d3 == bd && i3 < win)) { bd = d3; win = i3; }
        if (win != i1 && lane == 0) out[ND + 2 + (size_t)row] = (float)win;
    }
}

// ---- k3b: full np rescan — one block per flagged row, INDEX-ONLY write ----
__launch_bounds__(256, 2)
__global__ void k_refine_full(const float* __restrict__ z, const float* __restrict__ cb,
                              const float* __restrict__ scp,
                              const uint* __restrict__ counts,
                              const uint* __restrict__ listFull, int capFull,
                              float* __restrict__ out) {
    __shared__ float zrow[256];
    __shared__ float avs[256];
    __shared__ int ais[256];

    uint n = counts[1];
    if (n > (uint)capFull) n = (uint)capFull;
    const int tid = threadIdx.x;

    for (uint j = blockIdx.x; j < n; j += gridDim.x) {
        int row = (int)listFull[j];
        __syncthreads();
        if (tid < 64)
            *(float4*)&zrow[tid * 4] = *(const float4*)(z + (size_t)row * DDIM + tid * 4);
        __syncthreads();

        float A = np_sq_sum256(zrow);

        float d0 = 0.f, d1 = 0.f, d2 = 0.f, d3 = 0.f;
        const float* c0 = cb + (size_t)(tid + 0) * DDIM;
        const float* c1 = cb + (size_t)(tid + 256) * DDIM;
        const float* c2 = cb + (size_t)(tid + 512) * DDIM;
        const float* c3 = cb + (size_t)(tid + 768) * DDIM;
        #pragma unroll 4
        for (int q = 0; q < 64; ++q) {
            float4 zz = *(const float4*)&zrow[q * 4];
            float4 a = *(const float4*)(c0 + q * 4);
            float4 b = *(const float4*)(c1 + q * 4);
            float4 c = *(const float4*)(c2 + q * 4);
            float4 d = *(const float4*)(c3 + q * 4);
            d0 = ffma(zz.x, a.x, d0); d0 = ffma(zz.y, a.y, d0);
            d0 = ffma(zz.z, a.z, d0); d0 = ffma(zz.w, a.w, d0);
            d1 = ffma(zz.x, b.x, d1); d1 = ffma(zz.y, b.y, d1);
            d1 = ffma(zz.z, b.z, d1); d1 = ffma(zz.w, b.w, d1);
            d2 = ffma(zz.x, c.x, d2); d2 = ffma(zz.y, c.y, d2);
            d2 = ffma(zz.z, c.z, d2); d2 = ffma(zz.w, c.w, d2);
            d3 = ffma(zz.x, d.x, d3); d3 = ffma(zz.y, d.y, d3);
            d3 = ffma(zz.z, d.z, d3); d3 = ffma(zz.w, d.w, d3);
        }
        float best = 1e30f; int bi = 0x7fffffff;
        float dd[4] = {d0, d1, d2, d3};
        #pragma unroll
        for (int kk = 0; kk < 4; ++kk) {
            int code = tid + kk * 256;
            float dist = fsub(fadd(A, scp[code]), fmul(2.f, dd[kk]));
            if (dist < best || (dist == best && code < bi)) { best = dist; bi = code; }
        }
        avs[tid] = best; ais[tid] = bi;
        __syncthreads();
        for (int off = 128; off; off >>= 1) {
            if (tid < off) {
                float o = avs[tid + off]; int oi = ais[tid + off];
                if (o < avs[tid] || (o == avs[tid] && oi < ais[tid])) {
                    avs[tid] = o; ais[tid] = oi;
                }
            }
            __syncthreads();
        }
        if (tid == 0) out[ND + 2 + (size_t)row] = (float)ais[0];
    }
}

// ---- k3c: sweep for worklist-overflow rows (normally a pure read pass) ----
__global__ void k_sweep(const float* __restrict__ z, const float* __restrict__ cb,
                        const float* __restrict__ scp, float* __restrict__ out) {
    int row = blockIdx.x * 256 + threadIdx.x;
    float v = out[ND + 2 + (size_t)row];
    if (v < 1048576.f) return;
    const float* zr = z + (size_t)row * DDIM;
    float A = np_sq_sum256(zr);
    float best = 1e30f; int win = 0x7fffffff;
    for (int code = 0; code < KCODES; ++code) {
        float dot = blas_dot256(zr, cb + (size_t)code * DDIM);
        float dist = fsub(fadd(A, scp[code]), fmul(2.f, dot));
        if (dist < best) { best = dist; win = code; }
    }
    out[ND + 2 + (size_t)row] = (float)win;
}

// ---- k_gather (LAST data pass): z_q for all rows from final indices ----
__global__ void k_gather(const float* __restrict__ cb, float* __restrict__ out) {
    __shared__ int idx[128];
    const int tid = threadIdx.x;
    const int blockRow = blockIdx.x * 128;
    if (tid < 128) idx[tid] = ((int)out[ND + 2 + (size_t)(blockRow + tid)]) & 1023;
    __syncthreads();
    float4* out4 = (float4*)out;
    const float4* cb4 = (const float4*)cb;
    #pragma unroll 4
    for (int i = 0; i < 32; ++i) {
        int q = i * 256 + tid;              // 128 rows x 64 float4
        int rowL = q >> 6, ch = q & 63;
        int code = idx[rowL];
        out4[(size_t)(blockRow + rowL) * 64 + ch] = cb4[(size_t)code * 64 + ch];
    }
}

// ---- k4: finalize scalar losses ----
__global__ void k_final(const double* __restrict__ lossA, const double* __restrict__ lossB,
                        const double* __restrict__ M2p, float* __restrict__ out) {
    if (threadIdx.x == 0) {
        double nd = (double)ND;
        out[ND] = (float)(*lossA / nd);
        out[ND + 1] = (float)((*lossB + (double)NROWS * (*M2p)) / nd);
    }
}

extern "C" void kernel_launch(void* const* d_in, const int* in_sizes, int n_in,
                              void* d_out, int out_size, void* d_ws, size_t ws_size,
                              hipStream_t stream) {
    const float* z = (const float*)d_in[0];
    const float* cb = (const float*)d_in[1];
    float* out = (float*)d_out;

    // ws: [0 lossA][8 lossB][16 M2p][24 counts(2)][32 mAcc 1KB]
    //     [2048 mvec][4096 scp 4KB][8192 cbh 512KB][532480 listFull | listTri]
    double* lossA = (double*)d_ws;
    double* lossB = lossA + 1;
    double* M2p   = lossA + 2;
    uint*   counts = (uint*)((char*)d_ws + 24);
    float*  mAcc  = (float*)((char*)d_ws + 32);
    float*  mvec  = (float*)((char*)d_ws + 2048);
    float*  scp   = (float*)((char*)d_ws + 4096);
    char*   cbh   = (char*)d_ws + 8192;

    size_t base = 8192 + 524288;
    size_t avail = ws_size > base ? ws_size - base : 0;
    int capFull = (int)(avail / 24);
    if (capFull > 32768) capFull = 32768;
    size_t fullBytes = ((size_t)capFull * 4 + 7) & ~(size_t)7;
    size_t availTri = avail > fullBytes ? avail - fullBytes : 0;
    int capTri = (int)(availTri / 8);
    if (capTri > 131072) capTri = 131072;

    uint*  listFull = (uint*)((char*)d_ws + base);
    uint2* listTri  = (uint2*)((char*)d_ws + base + fullBytes);

    hipMemsetAsync(d_ws, 0, 1056, stream);
    k_prep<<<148, 256, 0, stream>>>(cb, cbh, scp, mAcc);
    k_meanfin<<<1, 256, 0, stream>>>(mAcc, mvec, M2p);
    k_main<<<NROWS / 128, 256, 0, stream>>>(z, cbh, scp, mvec, out,
                                            counts, listTri, listFull,
                                            capTri, capFull, lossA, lossB);
    k_refine_tri<<<512, 256, 0, stream>>>(z, cb, scp, counts, listTri, capTri, out);
    k_refine_full<<<1024, 256, 0, stream>>>(z, cb, scp, counts, listFull, capFull, out);
    k_sweep<<<NROWS / 256, 256, 0, stream>>>(z, cb, scp, out);
    k_gather<<<NROWS / 128, 256, 0, stream>>>(cb, out);
    k_final<<<1, 64, 0, stream>>>(lossA, lossB, M2p, out);
}

// Round 16
// 938.346 us; speedup vs baseline: 1.3055x; 1.2744x over previous
//
#include <hip/hip_runtime.h>

// VQ layer: N=262144 rows (D=256), K=1024 codes.
// out (FLOAT32): [z_q: N*D][loss_vq][loss_mean][indices(as float): N]
//
// Indices = numpy-f32 argmin of d = fl32( fl32(A_np + s_np,k) - fl32(2*M_k) ),
// tie -> lowest index. fp16-MFMA pass (keyed top-3) decides rows with top-2
// gap >= M1F; flagged rows resolved by exact np-emulation kernels (index-only).
// Round 16: single change vs r15 -- k_main gets __launch_bounds__(256)
// (max-threads only). r15's spill came from hipcc's DEFAULT 1024-thread
// assumption capping VGPR at 64; (256) lifts the cap (no spill) while the
// 38.4KB LDS still allows 4 blocks/CU -> 16 waves/CU.

#define NROWS 262144
#define KCODES 1024
#define DDIM 256
#define ND ((size_t)NROWS * (size_t)DDIM)
#define M1F 6e-4f

typedef unsigned int uint;
typedef _Float16 f16x8 __attribute__((ext_vector_type(8)));
typedef float f32x4v __attribute__((ext_vector_type(4)));

// ---- IEEE-exact f32 ops: NON-volatile (schedulable, never contracted) ----
__device__ inline float fadd(float a, float b) {
    float d; asm("v_add_f32 %0, %1, %2" : "=v"(d) : "v"(a), "v"(b)); return d;
}
__device__ inline float fmul(float a, float b) {
    float d; asm("v_mul_f32 %0, %1, %2" : "=v"(d) : "v"(a), "v"(b)); return d;
}
__device__ inline float fsub(float a, float b) {
    float d; asm("v_sub_f32 %0, %1, %2" : "=v"(d) : "v"(a), "v"(b)); return d;
}
__device__ inline float ffma(float a, float b, float c) {
    float d; asm("v_fma_f32 %0, %1, %2, %3" : "=v"(d) : "v"(a), "v"(b), "v"(c)); return d;
}

// numpy pairwise sum of a[i]^2, n=256 (exact np order).
__device__ float np_sq_sum256(const float* __restrict__ a) {
    float tot[2];
    #pragma unroll 1
    for (int h = 0; h < 2; ++h) {
        const float* p = a + h * 128;
        float r[8];
        #pragma unroll
        for (int j = 0; j < 8; ++j) r[j] = fmul(p[j], p[j]);
        #pragma unroll 1
        for (int i = 8; i < 128; i += 8)
            #pragma unroll
            for (int j = 0; j < 8; ++j) r[j] = fadd(r[j], fmul(p[i + j], p[i + j]));
        tot[h] = fadd(fadd(fadd(r[0], r[1]), fadd(r[2], r[3])),
                      fadd(fadd(r[4], r[5]), fadd(r[6], r[7])));
    }
    return fadd(tot[0], tot[1]);
}

// BLAS-style f32 dot: single-accumulator serial FMA chain, ascending k.
__device__ float blas_dot256(const float* __restrict__ zr, const float* __restrict__ cr) {
    float dot = 0.f;
    #pragma unroll 4
    for (int d4 = 0; d4 < 64; ++d4) {
        float4 zz = *(const float4*)(zr + d4 * 4);
        float4 cc = *(const float4*)(cr + d4 * 4);
        dot = ffma(zz.x, cc.x, dot); dot = ffma(zz.y, cc.y, dot);
        dot = ffma(zz.z, cc.z, dot); dot = ffma(zz.w, cc.w, dot);
    }
    return dot;
}

// ---- k_prep: fused {cvt 32-code swizzled tiles (128 blk), codestats (4), colsum (16)} ----
__global__ void k_prep(const float* __restrict__ cb, char* __restrict__ cbh,
                       float* __restrict__ scp, float* __restrict__ mAcc) {
    int bx = blockIdx.x;
    if (bx < 128) {
        int g = bx * 256 + threadIdx.x;          // 0..32767 f16x8 groups
        int t = g >> 10, c = (g >> 5) & 31, j = g & 31;
        const float* s = cb + (size_t)(t * 32 + c) * DDIM + j * 8;
        float4 v0 = *(const float4*)s, v1 = *(const float4*)(s + 4);
        f16x8 h;
        h[0] = (_Float16)(v0.x * 1024.f); h[1] = (_Float16)(v0.y * 1024.f);
        h[2] = (_Float16)(v0.z * 1024.f); h[3] = (_Float16)(v0.w * 1024.f);
        h[4] = (_Float16)(v1.x * 1024.f); h[5] = (_Float16)(v1.y * 1024.f);
        h[6] = (_Float16)(v1.z * 1024.f); h[7] = (_Float16)(v1.w * 1024.f);
        uint byte = (uint)(c * 512 + j * 16) ^ (uint)((c & 7) << 4);
        *(f16x8*)(cbh + (size_t)t * 16384 + byte) = h;
    } else if (bx < 132) {
        int code = (bx - 128) * 256 + threadIdx.x;
        if (code < KCODES) scp[code] = np_sq_sum256(cb + (size_t)code * DDIM);
    } else {
        int d = threadIdx.x;
        int b = bx - 132;
        float s = 0.f;
        for (int i = 0; i < 64; ++i) s += cb[(size_t)(b * 64 + i) * DDIM + d];
        atomicAdd(&mAcc[d], s);
    }
}

// ---- k1c: finalize mean vector + ||m||^2 ----
__global__ void k_meanfin(const float* __restrict__ mAcc,
                          float* __restrict__ mvec, double* __restrict__ M2p) {
    __shared__ double red[256];
    int d = threadIdx.x;
    float m = mAcc[d] * (1.0f / 1024.0f);
    mvec[d] = m;
    red[d] = (double)m * (double)m;
    __syncthreads();
    for (int off = 128; off; off >>= 1) {
        if (d < off) red[d] += red[d + off];
        __syncthreads();
    }
    if (d == 0) *M2p = red[0];
}

#define GLOAD_LDS16(g, l) \
    __builtin_amdgcn_global_load_lds( \
        (const __attribute__((address_space(1))) void*)(g), \
        (__attribute__((address_space(3))) void*)(l), 16, 0, 0)

// ---- k2: main MFMA pass (256 thr, 128 rows, 32-code tiles) ----
__launch_bounds__(256)
__global__ void k_main(const float* __restrict__ z, const char* __restrict__ cbh,
                       const float* __restrict__ sc, const float* __restrict__ mvec,
                       float* __restrict__ out, uint* __restrict__ counts,
                       uint2* __restrict__ listTri, uint* __restrict__ listFull,
                       int capTri, int capFull,
                       double* __restrict__ lossA, double* __restrict__ lossB) {
    __shared__ char tiles[2][16384] __attribute__((aligned(16)));
    __shared__ float sc_lds[1024];
    __shared__ float statA[128], statZM[128];
    __shared__ float lred[2];

    const int tid = threadIdx.x;
    const int wave = tid >> 6;          // 0..3
    const int lane = tid & 63;
    const int l15 = lane & 15;
    const int lg = lane >> 4;
    const int blockRow = blockIdx.x * 128;

    if (tid < 2) lred[tid] = 0.f;
    for (int i = tid; i < 1024; i += 256) sc_lds[i] = sc[i];

    // --- z rows -> fp16 A-frags; per-row sum(z^2), z.m (losses) ---
    f16x8 za[2][8];
    #pragma unroll
    for (int m = 0; m < 2; ++m) {
        const float* zr = z + (size_t)(blockRow + wave * 32 + m * 16 + l15) * DDIM;
        float a2 = 0.f, zm = 0.f;
        #pragma unroll
        for (int kk = 0; kk < 8; ++kk) {
            int d0 = kk * 32 + lg * 8;
            float4 v0 = *(const float4*)(zr + d0);
            float4 v1 = *(const float4*)(zr + d0 + 4);
            float4 w0 = *(const float4*)(mvec + d0);
            float4 w1 = *(const float4*)(mvec + d0 + 4);
            a2 += v0.x * v0.x + v0.y * v0.y + v0.z * v0.z + v0.w * v0.w;
            a2 += v1.x * v1.x + v1.y * v1.y + v1.z * v1.z + v1.w * v1.w;
            zm += v0.x * w0.x + v0.y * w0.y + v0.z * w0.z + v0.w * w0.w;
            zm += v1.x * w1.x + v1.y * w1.y + v1.z * w1.z + v1.w * w1.w;
            f16x8 h;
            h[0] = (_Float16)v0.x; h[1] = (_Float16)v0.y;
            h[2] = (_Float16)v0.z; h[3] = (_Float16)v0.w;
            h[4] = (_Float16)v1.x; h[5] = (_Float16)v1.y;
            h[6] = (_Float16)v1.z; h[7] = (_Float16)v1.w;
            za[m][kk] = h;
        }
        a2 += __shfl_xor(a2, 16); a2 += __shfl_xor(a2, 32);
        zm += __shfl_xor(zm, 16); zm += __shfl_xor(zm, 32);
        if (lg == 0) {
            statA[wave * 32 + m * 16 + l15] = a2;
            statZM[wave * 32 + m * 16 + l15] = zm;
        }
    }
    __syncthreads();   // drains all prior vm loads -> vmcnt bookkeeping exact

    float k1v[2][2][4], k2v[2][2][4], k3v[2][2][4];
    #pragma unroll
    for (int n = 0; n < 2; ++n)
        #pragma unroll
        for (int m = 0; m < 2; ++m)
            #pragma unroll
            for (int r = 0; r < 4; ++r) {
                k1v[n][m][r] = 3e38f; k2v[n][m][r] = 3e38f; k3v[n][m][r] = 3e38f;
            }

    // DMA stage: 4 x 16B per thread per tile (4 waves x 4KB = 16KB)
    const char* gsrc0 = cbh + (size_t)wave * 4096 + (size_t)lane * 16;
    #define STAGE(T, BUF) { \
        const char* g_ = gsrc0 + (size_t)(T) * 16384; \
        char* l_ = &tiles[BUF][wave * 4096]; \
        _Pragma("unroll") \
        for (int i_ = 0; i_ < 4; ++i_) GLOAD_LDS16(g_ + i_ * 1024, l_ + i_ * 1024); \
    }

    #define COMPUTE(T, BUF) { \
        f32x4v acc[2][2]; \
        _Pragma("unroll") \
        for (int m = 0; m < 2; ++m) \
            _Pragma("unroll") \
            for (int n = 0; n < 2; ++n) acc[m][n] = (f32x4v){0.f, 0.f, 0.f, 0.f}; \
        const char* tb = &tiles[BUF][0]; \
        _Pragma("unroll") \
        for (int kk = 0; kk < 8; ++kk) { \
            _Pragma("unroll") \
            for (int n = 0; n < 2; ++n) { \
                int lcode = n * 16 + l15; \
                uint byte = (uint)(lcode * 512 + kk * 64 + lg * 16) ^ (uint)((lcode & 7) << 4); \
                f16x8 b = *(const f16x8*)(tb + byte); \
                acc[0][n] = __builtin_amdgcn_mfma_f32_16x16x32_f16(za[0][kk], b, acc[0][n], 0, 0, 0); \
                acc[1][n] = __builtin_amdgcn_mfma_f32_16x16x32_f16(za[1][kk], b, acc[1][n], 0, 0, 0); \
            } \
        } \
        int tbase = (T) * 32; \
        _Pragma("unroll") \
        for (int n = 0; n < 2; ++n) { \
            int codev = tbase + n * 16 + l15; \
            float scv = sc_lds[codev]; \
            _Pragma("unroll") \
            for (int m = 0; m < 2; ++m) \
                _Pragma("unroll") \
                for (int r = 0; r < 4; ++r) { \
                    float s = fmaf(acc[m][n][r], -0.001953125f, scv); \
                    uint kb = (__float_as_uint(s) & 0xFFFFFC00u) | (uint)codev; \
                    float k = __uint_as_float(kb); \
                    float o1 = k1v[n][m][r], o2 = k2v[n][m][r]; \
                    k3v[n][m][r] = __builtin_amdgcn_fmed3f(o2, k3v[n][m][r], k); \
                    k2v[n][m][r] = __builtin_amdgcn_fmed3f(o1, o2, k); \
                    k1v[n][m][r] = fminf(o1, k); \
                } \
        } \
    }

    STAGE(0, 0);
    #pragma unroll 1
    for (int t = 0; t < 31; ++t) {
        STAGE(t + 1, (t + 1) & 1);
        asm volatile("s_waitcnt vmcnt(4)" ::: "memory");
        __builtin_amdgcn_s_barrier();
        __builtin_amdgcn_sched_barrier(0);
        COMPUTE(t, t & 1);
        __builtin_amdgcn_sched_barrier(0);
        __builtin_amdgcn_s_barrier();
    }
    asm volatile("s_waitcnt vmcnt(0)" ::: "memory");
    __builtin_amdgcn_s_barrier();
    __builtin_amdgcn_sched_barrier(0);
    COMPUTE(31, 1);

    // --- fold n=0/n=1 key banks, then cross-lane top-3 merge + writeback ---
    float lA = 0.f, lB = 0.f;
    #pragma unroll
    for (int m = 0; m < 2; ++m)
        #pragma unroll
        for (int r = 0; r < 4; ++r) {
            float x1 = k1v[0][m][r], x2 = k2v[0][m][r], x3 = k3v[0][m][r];
            float y1 = k1v[1][m][r], y2 = k2v[1][m][r], y3 = k3v[1][m][r];
            float mx = fmaxf(x1, y1);
            float a3 = fminf(fminf(__builtin_amdgcn_fmed3f(x2, y2, mx), x3), y3);
            float a2 = fminf(fminf(mx, x2), y2);
            float a1 = fminf(x1, y1);
            #pragma unroll
            for (int mk = 1; mk <= 8; mk <<= 1) {
                float b1 = __shfl_xor(a1, mk);
                float b2 = __shfl_xor(a2, mk);
                float b3 = __shfl_xor(a3, mk);
                float mx2 = fmaxf(a1, b1);
                float n3 = fminf(fminf(__builtin_amdgcn_fmed3f(a2, b2, mx2), a3), b3);
                float n2 = fminf(fminf(mx2, a2), b2);
                a1 = fminf(a1, b1); a2 = n2; a3 = n3;
            }
            if (l15 == 0) {
                int rowL = wave * 32 + m * 16 + lg * 4 + r;
                int row = blockRow + rowL;
                int i1 = (int)(__float_as_uint(a1) & 1023u);
                int i2 = (int)(__float_as_uint(a2) & 1023u);
                int i3 = (int)(__float_as_uint(a3) & 1023u);
                int flag = (a3 - a1 < M1F) ? 2 : ((a2 - a1 < M1F) ? 1 : 0);
                float slotval = (float)i1;
                if (flag == 2) {
                    uint p = atomicAdd(&counts[1], 1u);
                    if (p < (uint)capFull) listFull[p] = (uint)row;
                    else slotval = (float)(i1 | (1 << 20));
                } else if (flag == 1) {
                    uint p = atomicAdd(&counts[0], 1u);
                    if (p < (uint)capTri)
                        listTri[p] = make_uint2((uint)row, (uint)(i1 | (i2 << 10) | (i3 << 20)));
                    else slotval = (float)(i1 | (1 << 20));
                }
                out[ND + 2 + (size_t)row] = slotval;
                lA += statA[rowL] + a1;
                lB += statA[rowL] - 2.f * statZM[rowL];
            }
        }
    if (l15 == 0) { atomicAdd(&lred[0], lA); atomicAdd(&lred[1], lB); }
    __syncthreads();
    if (tid == 0) {
        atomicAdd(lossA, (double)lred[0]);
        atomicAdd(lossB, (double)lred[1]);
    }
}

// ---- k3a: triple refine — one WAVE per flagged row, INDEX-ONLY write ----
__launch_bounds__(256)
__global__ void k_refine_tri(const float* __restrict__ z, const float* __restrict__ cb,
                             const float* __restrict__ scp,
                             const uint* __restrict__ counts,
                             const uint2* __restrict__ listTri, int capTri,
                             float* __restrict__ out) {
    __shared__ float B[4][4][256];
    const int wv = threadIdx.x >> 6;
    const int lane = threadIdx.x & 63;
    uint n = counts[0];
    if (n > (uint)capTri) n = (uint)capTri;
    uint nw = gridDim.x * 4;
    for (uint it = blockIdx.x * 4 + wv; it < n; it += nw) {
        uint2 e = listTri[it];
        int row = (int)e.x;
        int i1 = (int)(e.y & 1023), i2 = (int)((e.y >> 10) & 1023), i3 = (int)((e.y >> 20) & 1023);
        *(float4*)&B[wv][0][lane * 4] = *(const float4*)(z + (size_t)row * DDIM + lane * 4);
        *(float4*)&B[wv][1][lane * 4] = *(const float4*)(cb + (size_t)i1 * DDIM + lane * 4);
        *(float4*)&B[wv][2][lane * 4] = *(const float4*)(cb + (size_t)i2 * DDIM + lane * 4);
        *(float4*)&B[wv][3][lane * 4] = *(const float4*)(cb + (size_t)i3 * DDIM + lane * 4);
        asm volatile("s_waitcnt vmcnt(0) lgkmcnt(0)" ::: "memory");
        __builtin_amdgcn_sched_barrier(0);
        float A = np_sq_sum256(B[wv][0]);
        float dA = 0.f, dB = 0.f, dC = 0.f;
        #pragma unroll 4
        for (int d4 = 0; d4 < 64; ++d4) {
            float4 zz = *(const float4*)&B[wv][0][d4 * 4];
            float4 ca = *(const float4*)&B[wv][1][d4 * 4];
            float4 cc = *(const float4*)&B[wv][2][d4 * 4];
            float4 cd = *(const float4*)&B[wv][3][d4 * 4];
            dA = ffma(zz.x, ca.x, dA); dA = ffma(zz.y, ca.y, dA);
            dA = ffma(zz.z, ca.z, dA); dA = ffma(zz.w, ca.w, dA);
            dB = ffma(zz.x, cc.x, dB); dB = ffma(zz.y, cc.y, dB);
            dB = ffma(zz.z, cc.z, dB); dB = ffma(zz.w, cc.w, dB);
            dC = ffma(zz.x, cd.x, dC); dC = ffma(zz.y, cd.y, dC);
            dC = ffma(zz.z, cd.z, dC); dC = ffma(zz.w, cd.w, dC);
        }
        float d1 = fsub(fadd(A, scp[i1]), fmul(2.f, dA));
        float d2 = fsub(fadd(A, scp[i2]), fmul(2.f, dB));
        float d3 = fsub(fadd(A, scp[i3]), fmul(2.f, dC));
        int win = i1; float bd = d1;
        if (d2 < bd || (d2 == bd && i2 < win)) { bd = d2; win = i2; }
        if (d3 < bd || (d3 == bd && i3 < win)) { bd = d3; win = i3; }
        if (win != i1 && lane == 0) out[ND + 2 + (size_t)row] = (float)win;
    }
}

// ---- k3b: full np rescan — one block per flagged row, INDEX-ONLY write ----
__launch_bounds__(256, 2)
__global__ void k_refine_full(const float* __restrict__ z, const float* __restrict__ cb,
                              const float* __restrict__ scp,
                              const uint* __restrict__ counts,
                              const uint* __restrict__ listFull, int capFull,
                              float* __restrict__ out) {
    __shared__ float zrow[256];
    __shared__ float avs[256];
    __shared__ int ais[256];

    uint n = counts[1];
    if (n > (uint)capFull) n = (uint)capFull;
    const int tid = threadIdx.x;

    for (uint j = blockIdx.x; j < n; j += gridDim.x) {
        int row = (int)listFull[j];
        __syncthreads();
        if (tid < 64)
            *(float4*)&zrow[tid * 4] = *(const float4*)(z + (size_t)row * DDIM + tid * 4);
        __syncthreads();

        float A = np_sq_sum256(zrow);

        float d0 = 0.f, d1 = 0.f, d2 = 0.f, d3 = 0.f;
        const float* c0 = cb + (size_t)(tid + 0) * DDIM;
        const float* c1 = cb + (size_t)(tid + 256) * DDIM;
        const float* c2 = cb + (size_t)(tid + 512) * DDIM;
        const float* c3 = cb + (size_t)(tid + 768) * DDIM;
        #pragma unroll 4
        for (int q = 0; q < 64; ++q) {
            float4 zz = *(const float4*)&zrow[q * 4];
            float4 a = *(const float4*)(c0 + q * 4);
            float4 b = *(const float4*)(c1 + q * 4);
            float4 c = *(const float4*)(c2 + q * 4);
            float4 d = *(const float4*)(c3 + q * 4);
            d0 = ffma(zz.x, a.x, d0); d0 = ffma(zz.y, a.y, d0);
            d0 = ffma(zz.z, a.z, d0); d0 = ffma(zz.w, a.w, d0);
            d1 = ffma(zz.x, b.x, d1); d1 = ffma(zz.y, b.y, d1);
            d1 = ffma(zz.z, b.z, d1); d1 = ffma(zz.w, b.w, d1);
            d2 = ffma(zz.x, c.x, d2); d2 = ffma(zz.y, c.y, d2);
            d2 = ffma(zz.z, c.z, d2); d2 = ffma(zz.w, c.w, d2);
            d3 = ffma(zz.x, d.x, d3); d3 = ffma(zz.y, d.y, d3);
            d3 = ffma(zz.z, d.z, d3); d3 = ffma(zz.w, d.w, d3);
        }
        float best = 1e30f; int bi = 0x7fffffff;
        float dd[4] = {d0, d1, d2, d3};
        #pragma unroll
        for (int kk = 0; kk < 4; ++kk) {
            int code = tid + kk * 256;
            float dist = fsub(fadd(A, scp[code]), fmul(2.f, dd[kk]));
            if (dist < best || (dist == best && code < bi)) { best = dist; bi = code; }
        }
        avs[tid] = best; ais[tid] = bi;
        __syncthreads();
        for (int off = 128; off; off >>= 1) {
            if (tid < off) {
                float o = avs[tid + off]; int oi = ais[tid + off];
                if (o < avs[tid] || (o == avs[tid] && oi < ais[tid])) {
                    avs[tid] = o; ais[tid] = oi;
                }
            }
            __syncthreads();
        }
        if (tid == 0) out[ND + 2 + (size_t)row] = (float)ais[0];
    }
}

// ---- k3c: sweep for worklist-overflow rows (normally a pure read pass) ----
__global__ void k_sweep(const float* __restrict__ z, const float* __restrict__ cb,
                        const float* __restrict__ scp, float* __restrict__ out) {
    int row = blockIdx.x * 256 + threadIdx.x;
    float v = out[ND + 2 + (size_t)row];
    if (v < 1048576.f) return;
    const float* zr = z + (size_t)row * DDIM;
    float A = np_sq_sum256(zr);
    float best = 1e30f; int win = 0x7fffffff;
    for (int code = 0; code < KCODES; ++code) {
        float dot = blas_dot256(zr, cb + (size_t)code * DDIM);
        float dist = fsub(fadd(A, scp[code]), fmul(2.f, dot));
        if (dist < best) { best = dist; win = code; }
    }
    out[ND + 2 + (size_t)row] = (float)win;
}

// ---- k_gather (LAST data pass): z_q for all rows from final indices ----
__global__ void k_gather(const float* __restrict__ cb, float* __restrict__ out) {
    __shared__ int idx[128];
    const int tid = threadIdx.x;
    const int blockRow = blockIdx.x * 128;
    if (tid < 128) idx[tid] = ((int)out[ND + 2 + (size_t)(blockRow + tid)]) & 1023;
    __syncthreads();
    float4* out4 = (float4*)out;
    const float4* cb4 = (const float4*)cb;
    #pragma unroll 4
    for (int i = 0; i < 32; ++i) {
        int q = i * 256 + tid;              // 128 rows x 64 float4
        int rowL = q >> 6, ch = q & 63;
        int code = idx[rowL];
        out4[(size_t)(blockRow + rowL) * 64 + ch] = cb4[(size_t)code * 64 + ch];
    }
}

// ---- k4: finalize scalar losses ----
__global__ void k_final(const double* __restrict__ lossA, const double* __restrict__ lossB,
                        const double* __restrict__ M2p, float* __restrict__ out) {
    if (threadIdx.x == 0) {
        double nd = (double)ND;
        out[ND] = (float)(*lossA / nd);
        out[ND + 1] = (float)((*lossB + (double)NROWS * (*M2p)) / nd);
    }
}

extern "C" void kernel_launch(void* const* d_in, const int* in_sizes, int n_in,
                              void* d_out, int out_size, void* d_ws, size_t ws_size,
                              hipStream_t stream) {
    const float* z = (const float*)d_in[0];
    const float* cb = (const float*)d_in[1];
    float* out = (float*)d_out;

    // ws: [0 lossA][8 lossB][16 M2p][24 counts(2)][32 mAcc 1KB]
    //     [2048 mvec][4096 scp 4KB][8192 cbh 512KB][532480 listFull | listTri]
    double* lossA = (double*)d_ws;
    double* lossB = lossA + 1;
    double* M2p   = lossA + 2;
    uint*   counts = (uint*)((char*)d_ws + 24);
    float*  mAcc  = (float*)((char*)d_ws + 32);
    float*  mvec  = (float*)((char*)d_ws + 2048);
    float*  scp   = (float*)((char*)d_ws + 4096);
    char*   cbh   = (char*)d_ws + 8192;

    size_t base = 8192 + 524288;
    size_t avail = ws_size > base ? ws_size - base : 0;
    int capFull = (int)(avail / 24);
    if (capFull > 32768) capFull = 32768;
    size_t fullBytes = ((size_t)capFull * 4 + 7) & ~(size_t)7;
    size_t availTri = avail > fullBytes ? avail - fullBytes : 0;
    int capTri = (int)(availTri / 8);
    if (capTri > 131072) capTri = 131072;

    uint*  listFull = (uint*)((char*)d_ws + base);
    uint2* listTri  = (uint2*)((char*)d_ws + base + fullBytes);

    hipMemsetAsync(d_ws, 0, 1056, stream);
    k_prep<<<148, 256, 0, stream>>>(cb, cbh, scp, mAcc);
    k_meanfin<<<1, 256, 0, stream>>>(mAcc, mvec, M2p);
    k_main<<<NROWS / 128, 256, 0, stream>>>(z, cbh, scp, mvec, out,
                                            counts, listTri, listFull,
                                            capTri, capFull, lossA, lossB);
    k_refine_tri<<<512, 256, 0, stream>>>(z, cb, scp, counts, listTri, capTri, out);
    k_refine_full<<<1024, 256, 0, stream>>>(z, cb, scp, counts, listFull, capFull, out);
    k_sweep<<<NROWS / 256, 256, 0, stream>>>(z, cb, scp, out);
    k_gather<<<NROWS / 128, 256, 0, stream>>>(cb, out);
    k_final<<<1, 64, 0, stream>>>(lossA, lossB, M2p, out);
}

// Round 17
// 929.198 us; speedup vs baseline: 1.3184x; 1.0098x over previous
//
#include <hip/hip_runtime.h>

// VQ layer: N=262144 rows (D=256), K=1024 codes.
// out (FLOAT32): [z_q: N*D][loss_vq][loss_mean][indices(as float): N]
//
// Round 17: k_main identical to r16 (best measured, ~480us). Tail changes
// only: refine_tri grid 2048 + un-pinned loads (r8's serialization pathology
// was still in its row loop), refine_full grid 2048, prep colsum 64 blocks.

#define NROWS 262144
#define KCODES 1024
#define DDIM 256
#define ND ((size_t)NROWS * (size_t)DDIM)
#define M1F 6e-4f

typedef unsigned int uint;
typedef _Float16 f16x8 __attribute__((ext_vector_type(8)));
typedef float f32x4v __attribute__((ext_vector_type(4)));

// ---- IEEE-exact f32 ops: NON-volatile (schedulable, never contracted) ----
__device__ inline float fadd(float a, float b) {
    float d; asm("v_add_f32 %0, %1, %2" : "=v"(d) : "v"(a), "v"(b)); return d;
}
__device__ inline float fmul(float a, float b) {
    float d; asm("v_mul_f32 %0, %1, %2" : "=v"(d) : "v"(a), "v"(b)); return d;
}
__device__ inline float fsub(float a, float b) {
    float d; asm("v_sub_f32 %0, %1, %2" : "=v"(d) : "v"(a), "v"(b)); return d;
}
__device__ inline float ffma(float a, float b, float c) {
    float d; asm("v_fma_f32 %0, %1, %2, %3" : "=v"(d) : "v"(a), "v"(b), "v"(c)); return d;
}

// numpy pairwise sum of a[i]^2, n=256 (exact np order).
__device__ float np_sq_sum256(const float* __restrict__ a) {
    float tot[2];
    #pragma unroll 1
    for (int h = 0; h < 2; ++h) {
        const float* p = a + h * 128;
        float r[8];
        #pragma unroll
        for (int j = 0; j < 8; ++j) r[j] = fmul(p[j], p[j]);
        #pragma unroll 1
        for (int i = 8; i < 128; i += 8)
            #pragma unroll
            for (int j = 0; j < 8; ++j) r[j] = fadd(r[j], fmul(p[i + j], p[i + j]));
        tot[h] = fadd(fadd(fadd(r[0], r[1]), fadd(r[2], r[3])),
                      fadd(fadd(r[4], r[5]), fadd(r[6], r[7])));
    }
    return fadd(tot[0], tot[1]);
}

// BLAS-style f32 dot: single-accumulator serial FMA chain, ascending k.
__device__ float blas_dot256(const float* __restrict__ zr, const float* __restrict__ cr) {
    float dot = 0.f;
    #pragma unroll 4
    for (int d4 = 0; d4 < 64; ++d4) {
        float4 zz = *(const float4*)(zr + d4 * 4);
        float4 cc = *(const float4*)(cr + d4 * 4);
        dot = ffma(zz.x, cc.x, dot); dot = ffma(zz.y, cc.y, dot);
        dot = ffma(zz.z, cc.z, dot); dot = ffma(zz.w, cc.w, dot);
    }
    return dot;
}

// ---- k_prep: fused {cvt 32-code swizzled tiles (128 blk), codestats (4), colsum (64)} ----
__global__ void k_prep(const float* __restrict__ cb, char* __restrict__ cbh,
                       float* __restrict__ scp, float* __restrict__ mAcc) {
    int bx = blockIdx.x;
    if (bx < 128) {
        int g = bx * 256 + threadIdx.x;          // 0..32767 f16x8 groups
        int t = g >> 10, c = (g >> 5) & 31, j = g & 31;
        const float* s = cb + (size_t)(t * 32 + c) * DDIM + j * 8;
        float4 v0 = *(const float4*)s, v1 = *(const float4*)(s + 4);
        f16x8 h;
        h[0] = (_Float16)(v0.x * 1024.f); h[1] = (_Float16)(v0.y * 1024.f);
        h[2] = (_Float16)(v0.z * 1024.f); h[3] = (_Float16)(v0.w * 1024.f);
        h[4] = (_Float16)(v1.x * 1024.f); h[5] = (_Float16)(v1.y * 1024.f);
        h[6] = (_Float16)(v1.z * 1024.f); h[7] = (_Float16)(v1.w * 1024.f);
        uint byte = (uint)(c * 512 + j * 16) ^ (uint)((c & 7) << 4);
        *(f16x8*)(cbh + (size_t)t * 16384 + byte) = h;
    } else if (bx < 132) {
        int code = (bx - 128) * 256 + threadIdx.x;
        if (code < KCODES) scp[code] = np_sq_sum256(cb + (size_t)code * DDIM);
    } else {
        int d = threadIdx.x;
        int b = bx - 132;                        // 64 blocks x 16 rows
        float s = 0.f;
        for (int i = 0; i < 16; ++i) s += cb[(size_t)(b * 16 + i) * DDIM + d];
        atomicAdd(&mAcc[d], s);
    }
}

// ---- k1c: finalize mean vector + ||m||^2 ----
__global__ void k_meanfin(const float* __restrict__ mAcc,
                          float* __restrict__ mvec, double* __restrict__ M2p) {
    __shared__ double red[256];
    int d = threadIdx.x;
    float m = mAcc[d] * (1.0f / 1024.0f);
    mvec[d] = m;
    red[d] = (double)m * (double)m;
    __syncthreads();
    for (int off = 128; off; off >>= 1) {
        if (d < off) red[d] += red[d + off];
        __syncthreads();
    }
    if (d == 0) *M2p = red[0];
}

#define GLOAD_LDS16(g, l) \
    __builtin_amdgcn_global_load_lds( \
        (const __attribute__((address_space(1))) void*)(g), \
        (__attribute__((address_space(3))) void*)(l), 16, 0, 0)

// ---- k2: main MFMA pass (256 thr, 128 rows, 32-code tiles) — r16 verbatim ----
__launch_bounds__(256)
__global__ void k_main(const float* __restrict__ z, const char* __restrict__ cbh,
                       const float* __restrict__ sc, const float* __restrict__ mvec,
                       float* __restrict__ out, uint* __restrict__ counts,
                       uint2* __restrict__ listTri, uint* __restrict__ listFull,
                       int capTri, int capFull,
                       double* __restrict__ lossA, double* __restrict__ lossB) {
    __shared__ char tiles[2][16384] __attribute__((aligned(16)));
    __shared__ float sc_lds[1024];
    __shared__ float statA[128], statZM[128];
    __shared__ float lred[2];

    const int tid = threadIdx.x;
    const int wave = tid >> 6;          // 0..3
    const int lane = tid & 63;
    const int l15 = lane & 15;
    const int lg = lane >> 4;
    const int blockRow = blockIdx.x * 128;

    if (tid < 2) lred[tid] = 0.f;
    for (int i = tid; i < 1024; i += 256) sc_lds[i] = sc[i];

    // --- z rows -> fp16 A-frags; per-row sum(z^2), z.m (losses) ---
    f16x8 za[2][8];
    #pragma unroll
    for (int m = 0; m < 2; ++m) {
        const float* zr = z + (size_t)(blockRow + wave * 32 + m * 16 + l15) * DDIM;
        float a2 = 0.f, zm = 0.f;
        #pragma unroll
        for (int kk = 0; kk < 8; ++kk) {
            int d0 = kk * 32 + lg * 8;
            float4 v0 = *(const float4*)(zr + d0);
            float4 v1 = *(const float4*)(zr + d0 + 4);
            float4 w0 = *(const float4*)(mvec + d0);
            float4 w1 = *(const float4*)(mvec + d0 + 4);
            a2 += v0.x * v0.x + v0.y * v0.y + v0.z * v0.z + v0.w * v0.w;
            a2 += v1.x * v1.x + v1.y * v1.y + v1.z * v1.z + v1.w * v1.w;
            zm += v0.x * w0.x + v0.y * w0.y + v0.z * w0.z + v0.w * w0.w;
            zm += v1.x * w1.x + v1.y * w1.y + v1.z * w1.z + v1.w * w1.w;
            f16x8 h;
            h[0] = (_Float16)v0.x; h[1] = (_Float16)v0.y;
            h[2] = (_Float16)v0.z; h[3] = (_Float16)v0.w;
            h[4] = (_Float16)v1.x; h[5] = (_Float16)v1.y;
            h[6] = (_Float16)v1.z; h[7] = (_Float16)v1.w;
            za[m][kk] = h;
        }
        a2 += __shfl_xor(a2, 16); a2 += __shfl_xor(a2, 32);
        zm += __shfl_xor(zm, 16); zm += __shfl_xor(zm, 32);
        if (lg == 0) {
            statA[wave * 32 + m * 16 + l15] = a2;
            statZM[wave * 32 + m * 16 + l15] = zm;
        }
    }
    __syncthreads();   // drains all prior vm loads -> vmcnt bookkeeping exact

    float k1v[2][2][4], k2v[2][2][4], k3v[2][2][4];
    #pragma unroll
    for (int n = 0; n < 2; ++n)
        #pragma unroll
        for (int m = 0; m < 2; ++m)
            #pragma unroll
            for (int r = 0; r < 4; ++r) {
                k1v[n][m][r] = 3e38f; k2v[n][m][r] = 3e38f; k3v[n][m][r] = 3e38f;
            }

    // DMA stage: 4 x 16B per thread per tile (4 waves x 4KB = 16KB)
    const char* gsrc0 = cbh + (size_t)wave * 4096 + (size_t)lane * 16;
    #define STAGE(T, BUF) { \
        const char* g_ = gsrc0 + (size_t)(T) * 16384; \
        char* l_ = &tiles[BUF][wave * 4096]; \
        _Pragma("unroll") \
        for (int i_ = 0; i_ < 4; ++i_) GLOAD_LDS16(g_ + i_ * 1024, l_ + i_ * 1024); \
    }

    #define COMPUTE(T, BUF) { \
        f32x4v acc[2][2]; \
        _Pragma("unroll") \
        for (int m = 0; m < 2; ++m) \
            _Pragma("unroll") \
            for (int n = 0; n < 2; ++n) acc[m][n] = (f32x4v){0.f, 0.f, 0.f, 0.f}; \
        const char* tb = &tiles[BUF][0]; \
        _Pragma("unroll") \
        for (int kk = 0; kk < 8; ++kk) { \
            _Pragma("unroll") \
            for (int n = 0; n < 2; ++n) { \
                int lcode = n * 16 + l15; \
                uint byte = (uint)(lcode * 512 + kk * 64 + lg * 16) ^ (uint)((lcode & 7) << 4); \
                f16x8 b = *(const f16x8*)(tb + byte); \
                acc[0][n] = __builtin_amdgcn_mfma_f32_16x16x32_f16(za[0][kk], b, acc[0][n], 0, 0, 0); \
                acc[1][n] = __builtin_amdgcn_mfma_f32_16x16x32_f16(za[1][kk], b, acc[1][n], 0, 0, 0); \
            } \
        } \
        int tbase = (T) * 32; \
        _Pragma("unroll") \
        for (int n = 0; n < 2; ++n) { \
            int codev = tbase + n * 16 + l15; \
            float scv = sc_lds[codev]; \
            _Pragma("unroll") \
            for (int m = 0; m < 2; ++m) \
                _Pragma("unroll") \
                for (int r = 0; r < 4; ++r) { \
                    float s = fmaf(acc[m][n][r], -0.001953125f, scv); \
                    uint kb = (__float_as_uint(s) & 0xFFFFFC00u) | (uint)codev; \
                    float k = __uint_as_float(kb); \
                    float o1 = k1v[n][m][r], o2 = k2v[n][m][r]; \
                    k3v[n][m][r] = __builtin_amdgcn_fmed3f(o2, k3v[n][m][r], k); \
                    k2v[n][m][r] = __builtin_amdgcn_fmed3f(o1, o2, k); \
                    k1v[n][m][r] = fminf(o1, k); \
                } \
        } \
    }

    STAGE(0, 0);
    #pragma unroll 1
    for (int t = 0; t < 31; ++t) {
        STAGE(t + 1, (t + 1) & 1);
        asm volatile("s_waitcnt vmcnt(4)" ::: "memory");
        __builtin_amdgcn_s_barrier();
        __builtin_amdgcn_sched_barrier(0);
        COMPUTE(t, t & 1);
        __builtin_amdgcn_sched_barrier(0);
        __builtin_amdgcn_s_barrier();
    }
    asm volatile("s_waitcnt vmcnt(0)" ::: "memory");
    __builtin_amdgcn_s_barrier();
    __builtin_amdgcn_sched_barrier(0);
    COMPUTE(31, 1);

    // --- fold n=0/n=1 key banks, then cross-lane top-3 merge + writeback ---
    float lA = 0.f, lB = 0.f;
    #pragma unroll
    for (int m = 0; m < 2; ++m)
        #pragma unroll
        for (int r = 0; r < 4; ++r) {
            float x1 = k1v[0][m][r], x2 = k2v[0][m][r], x3 = k3v[0][m][r];
            float y1 = k1v[1][m][r], y2 = k2v[1][m][r], y3 = k3v[1][m][r];
            float mx = fmaxf(x1, y1);
            float a3 = fminf(fminf(__builtin_amdgcn_fmed3f(x2, y2, mx), x3), y3);
            float a2 = fminf(fminf(mx, x2), y2);
            float a1 = fminf(x1, y1);
            #pragma unroll
            for (int mk = 1; mk <= 8; mk <<= 1) {
                float b1 = __shfl_xor(a1, mk);
                float b2 = __shfl_xor(a2, mk);
                float b3 = __shfl_xor(a3, mk);
                float mx2 = fmaxf(a1, b1);
                float n3 = fminf(fminf(__builtin_amdgcn_fmed3f(a2, b2, mx2), a3), b3);
                float n2 = fminf(fminf(mx2, a2), b2);
                a1 = fminf(a1, b1); a2 = n2; a3 = n3;
            }
            if (l15 == 0) {
                int rowL = wave * 32 + m * 16 + lg * 4 + r;
                int row = blockRow + rowL;
                int i1 = (int)(__float_as_uint(a1) & 1023u);
                int i2 = (int)(__float_as_uint(a2) & 1023u);
                int i3 = (int)(__float_as_uint(a3) & 1023u);
                int flag = (a3 - a1 < M1F) ? 2 : ((a2 - a1 < M1F) ? 1 : 0);
                float slotval = (float)i1;
                if (flag == 2) {
                    uint p = atomicAdd(&counts[1], 1u);
                    if (p < (uint)capFull) listFull[p] = (uint)row;
                    else slotval = (float)(i1 | (1 << 20));
                } else if (flag == 1) {
                    uint p = atomicAdd(&counts[0], 1u);
                    if (p < (uint)capTri)
                        listTri[p] = make_uint2((uint)row, (uint)(i1 | (i2 << 10) | (i3 << 20)));
                    else slotval = (float)(i1 | (1 << 20));
                }
                out[ND + 2 + (size_t)row] = slotval;
                lA += statA[rowL] + a1;
                lB += statA[rowL] - 2.f * statZM[rowL];
            }
        }
    if (l15 == 0) { atomicAdd(&lred[0], lA); atomicAdd(&lred[1], lB); }
    __syncthreads();
    if (tid == 0) {
        atomicAdd(lossA, (double)lred[0]);
        atomicAdd(lossB, (double)lred[1]);
    }
}

// ---- k3a: triple refine — one WAVE per flagged row; UN-PINNED loads ----
__launch_bounds__(256)
__global__ void k_refine_tri(const float* __restrict__ z, const float* __restrict__ cb,
                             const float* __restrict__ scp,
                             const uint* __restrict__ counts,
                             const uint2* __restrict__ listTri, int capTri,
                             float* __restrict__ out) {
    __shared__ float B[4][4][256];
    const int wv = threadIdx.x >> 6;
    const int lane = threadIdx.x & 63;
    uint n = counts[0];
    if (n > (uint)capTri) n = (uint)capTri;
    uint nw = gridDim.x * 4;
    for (uint it = blockIdx.x * 4 + wv; it < n; it += nw) {
        uint2 e = listTri[it];
        int row = (int)e.x;
        int i1 = (int)(e.y & 1023), i2 = (int)((e.y >> 10) & 1023), i3 = (int)((e.y >> 20) & 1023);
        *(float4*)&B[wv][0][lane * 4] = *(const float4*)(z + (size_t)row * DDIM + lane * 4);
        *(float4*)&B[wv][1][lane * 4] = *(const float4*)(cb + (size_t)i1 * DDIM + lane * 4);
        *(float4*)&B[wv][2][lane * 4] = *(const float4*)(cb + (size_t)i2 * DDIM + lane * 4);
        *(float4*)&B[wv][3][lane * 4] = *(const float4*)(cb + (size_t)i3 * DDIM + lane * 4);
        asm volatile("s_waitcnt vmcnt(0) lgkmcnt(0)" ::: "memory");
        float A = np_sq_sum256(B[wv][0]);
        float dA = 0.f, dB = 0.f, dC = 0.f;
        #pragma unroll 4
        for (int d4 = 0; d4 < 64; ++d4) {
            float4 zz = *(const float4*)&B[wv][0][d4 * 4];
            float4 ca = *(const float4*)&B[wv][1][d4 * 4];
            float4 cc = *(const float4*)&B[wv][2][d4 * 4];
            float4 cd = *(const float4*)&B[wv][3][d4 * 4];
            dA = ffma(zz.x, ca.x, dA); dA = ffma(zz.y, ca.y, dA);
            dA = ffma(zz.z, ca.z, dA); dA = ffma(zz.w, ca.w, dA);
            dB = ffma(zz.x, cc.x, dB); dB = ffma(zz.y, cc.y, dB);
            dB = ffma(zz.z, cc.z, dB); dB = ffma(zz.w, cc.w, dB);
            dC = ffma(zz.x, cd.x, dC); dC = ffma(zz.y, cd.y, dC);
            dC = ffma(zz.z, cd.z, dC); dC = ffma(zz.w, cd.w, dC);
        }
        float d1 = fsub(fadd(A, scp[i1]), fmul(2.f, dA));
        float d2 = fsub(fadd(A, scp[i2]), fmul(2.f, dB));
        float d3 = fsub(fadd(A, scp[i3]), fmul(2.f, dC));
        int win = i1; float bd = d1;
        if (d2 < bd || (d2 == bd && i2 < win)) { bd = d2; win = i2; }
        if (d3 < bd || (d3 == bd && i3 < win)) { bd = d3; win = i3; }
        if (win != i1 && lane == 0) out[ND + 2 + (size_t)row] = (float)win;
    }
}

// ---- k3b: full np rescan — one block per flagged row, INDEX-ONLY write ----
__launch_bounds__(256, 2)
__global__ void k_refine_full(const float* __restrict__ z, const float* __restrict__ cb,
                              const float* __restrict__ scp,
                              const uint* __restrict__ counts,
                              const uint* __restrict__ listFull, int capFull,
                              float* __restrict__ out) {
    __shared__ float zrow[256];
    __shared__ float avs[256];
    __shared__ int ais[256];

    uint n = counts[1];
    if (n > (uint)capFull) n = (uint)capFull;
    const int tid = threadIdx.x;

    for (uint j = blockIdx.x; j < n; j += gridDim.x) {
        int row = (int)listFull[j];
        __syncthreads();
        if (tid < 64)
            *(float4*)&zrow[tid * 4] = *(const float4*)(z + (size_t)row * DDIM + tid * 4);
        __syncthreads();

        float A = np_sq_sum256(zrow);

        float d0 = 0.f, d1 = 0.f, d2 = 0.f, d3 = 0.f;
        const float* c0 = cb + (size_t)(tid + 0) * DDIM;
        const float* c1 = cb + (size_t)(tid + 256) * DDIM;
        const float* c2 = cb + (size_t)(tid + 512) * DDIM;
        const float* c3 = cb + (size_t)(tid + 768) * DDIM;
        #pragma unroll 4
        for (int q = 0; q < 64; ++q) {
            float4 zz = *(const float4*)&zrow[q * 4];
            float4 a = *(const float4*)(c0 + q * 4);
            float4 b = *(const float4*)(c1 + q * 4);
            float4 c = *(const float4*)(c2 + q * 4);
            float4 d = *(const float4*)(c3 + q * 4);
            d0 = ffma(zz.x, a.x, d0); d0 = ffma(zz.y, a.y, d0);
            d0 = ffma(zz.z, a.z, d0); d0 = ffma(zz.w, a.w, d0);
            d1 = ffma(zz.x, b.x, d1); d1 = ffma(zz.y, b.y, d1);
            d1 = ffma(zz.z, b.z, d1); d1 = ffma(zz.w, b.w, d1);
            d2 = ffma(zz.x, c.x, d2); d2 = ffma(zz.y, c.y, d2);
            d2 = ffma(zz.z, c.z, d2); d2 = ffma(zz.w, c.w, d2);
            d3 = ffma(zz.x, d.x, d3); d3 = ffma(zz.y, d.y, d3);
            d3 = ffma(zz.z, d.z, d3); d3 = ffma(zz.w, d.w, d3);
        }
        float best = 1e30f; int bi = 0x7fffffff;
        float dd[4] = {d0, d1, d2, d3};
        #pragma unroll
        for (int kk = 0; kk < 4; ++kk) {
            int code = tid + kk * 256;
            float dist = fsub(fadd(A, scp[code]), fmul(2.f, dd[kk]));
            if (dist < best || (dist == best && code < bi)) { best = dist; bi = code; }
        }
        avs[tid] = best; ais[tid] = bi;
        __syncthreads();
        for (int off = 128; off; off >>= 1) {
            if (tid < off) {
                float o = avs[tid + off]; int oi = ais[tid + off];
                if (o < avs[tid] || (o == avs[tid] && oi < ais[tid])) {
                    avs[tid] = o; ais[tid] = oi;
                }
            }
            __syncthreads();
        }
        if (tid == 0) out[ND + 2 + (size_t)row] = (float)ais[0];
    }
}

// ---- k3c: sweep for worklist-overflow rows (normally a pure read pass) ----
__global__ void k_sweep(const float* __restrict__ z, const float* __restrict__ cb,
                        const float* __restrict__ scp, float* __restrict__ out) {
    int row = blockIdx.x * 256 + threadIdx.x;
    float v = out[ND + 2 + (size_t)row];
    if (v < 1048576.f) return;
    const float* zr = z + (size_t)row * DDIM;
    float A = np_sq_sum256(zr);
    float best = 1e30f; int win = 0x7fffffff;
    for (int code = 0; code < KCODES; ++code) {
        float dot = blas_dot256(zr, cb + (size_t)code * DDIM);
        float dist = fsub(fadd(A, scp[code]), fmul(2.f, dot));
        if (dist < best) { best = dist; win = code; }
    }
    out[ND + 2 + (size_t)row] = (float)win;
}

// ---- k_gather (LAST data pass): z_q for all rows from final indices ----
__global__ void k_gather(const float* __restrict__ cb, float* __restrict__ out) {
    __shared__ int idx[128];
    const int tid = threadIdx.x;
    const int blockRow = blockIdx.x * 128;
    if (tid < 128) idx[tid] = ((int)out[ND + 2 + (size_t)(blockRow + tid)]) & 1023;
    __syncthreads();
    float4* out4 = (float4*)out;
    const float4* cb4 = (const float4*)cb;
    #pragma unroll 4
    for (int i = 0; i < 32; ++i) {
        int q = i * 256 + tid;              // 128 rows x 64 float4
        int rowL = q >> 6, ch = q & 63;
        int code = idx[rowL];
        out4[(size_t)(blockRow + rowL) * 64 + ch] = cb4[(size_t)code * 64 + ch];
    }
}

// ---- k4: finalize scalar losses ----
__global__ void k_final(const double* __restrict__ lossA, const double* __restrict__ lossB,
                        const double* __restrict__ M2p, float* __restrict__ out) {
    if (threadIdx.x == 0) {
        double nd = (double)ND;
        out[ND] = (float)(*lossA / nd);
        out[ND + 1] = (float)((*lossB + (double)NROWS * (*M2p)) / nd);
    }
}

extern "C" void kernel_launch(void* const* d_in, const int* in_sizes, int n_in,
                              void* d_out, int out_size, void* d_ws, size_t ws_size,
                              hipStream_t stream) {
    const float* z = (const float*)d_in[0];
    const float* cb = (const float*)d_in[1];
    float* out = (float*)d_out;

    // ws: [0 lossA][8 lossB][16 M2p][24 counts(2)][32 mAcc 1KB]
    //     [2048 mvec][4096 scp 4KB][8192 cbh 512KB][532480 listFull | listTri]
    double* lossA = (double*)d_ws;
    double* lossB = lossA + 1;
    double* M2p   = lossA + 2;
    uint*   counts = (uint*)((char*)d_ws + 24);
    float*  mAcc  = (float*)((char*)d_ws + 32);
    float*  mvec  = (float*)((char*)d_ws + 2048);
    float*  scp   = (float*)((char*)d_ws + 4096);
    char*   cbh   = (char*)d_ws + 8192;

    size_t base = 8192 + 524288;
    size_t avail = ws_size > base ? ws_size - base : 0;
    int capFull = (int)(avail / 24);
    if (capFull > 32768) capFull = 32768;
    size_t fullBytes = ((size_t)capFull * 4 + 7) & ~(size_t)7;
    size_t availTri = avail > fullBytes ? avail - fullBytes : 0;
    int capTri = (int)(availTri / 8);
    if (capTri > 131072) capTri = 131072;

    uint*  listFull = (uint*)((char*)d_ws + base);
    uint2* listTri  = (uint2*)((char*)d_ws + base + fullBytes);

    hipMemsetAsync(d_ws, 0, 1056, stream);
    k_prep<<<196, 256, 0, stream>>>(cb, cbh, scp, mAcc);
    k_meanfin<<<1, 256, 0, stream>>>(mAcc, mvec, M2p);
    k_main<<<NROWS / 128, 256, 0, stream>>>(z, cbh, scp, mvec, out,
                                            counts, listTri, listFull,
                                            capTri, capFull, lossA, lossB);
    k_refine_tri<<<2048, 256, 0, stream>>>(z, cb, scp, counts, listTri, capTri, out);
    k_refine_full<<<2048, 256, 0, stream>>>(z, cb, scp, counts, listFull, capFull, out);
    k_sweep<<<NROWS / 256, 256, 0, stream>>>(z, cb, scp, out);
    k_gather<<<NROWS / 128, 256, 0, stream>>>(cb, out);
    k_final<<<1, 64, 0, stream>>>(lossA, lossB, M2p, out);
}

// Round 18
// 834.315 us; speedup vs baseline: 1.4683x; 1.1137x over previous
//
#include <hip/hip_runtime.h>

// VQ layer: N=262144 rows (D=256), K=1024 codes.
// out (FLOAT32): [z_q: N*D][loss_vq][loss_mean][indices(as float): N]
//
// Round 18: tail collapsed to ONE kernel. k_main (r16 core, unchanged
// schedule) writes encoded slots: flag0 -> i1; flag1 -> i1|i2<<10|1<<20
// (pair-refine); flag2 -> i1|2<<20 (full rescan). k_tail decodes, refines
// in-block (no worklists/atomics), writes float indices, gathers z_q.
// Launches: prep, meanfin, main, tail, final.

#define NROWS 262144
#define KCODES 1024
#define DDIM 256
#define ND ((size_t)NROWS * (size_t)DDIM)
#define M1F 6e-4f

typedef unsigned int uint;
typedef _Float16 f16x8 __attribute__((ext_vector_type(8)));
typedef float f32x4v __attribute__((ext_vector_type(4)));

// ---- IEEE-exact f32 ops: NON-volatile (schedulable, never contracted) ----
__device__ inline float fadd(float a, float b) {
    float d; asm("v_add_f32 %0, %1, %2" : "=v"(d) : "v"(a), "v"(b)); return d;
}
__device__ inline float fmul(float a, float b) {
    float d; asm("v_mul_f32 %0, %1, %2" : "=v"(d) : "v"(a), "v"(b)); return d;
}
__device__ inline float fsub(float a, float b) {
    float d; asm("v_sub_f32 %0, %1, %2" : "=v"(d) : "v"(a), "v"(b)); return d;
}
__device__ inline float ffma(float a, float b, float c) {
    float d; asm("v_fma_f32 %0, %1, %2, %3" : "=v"(d) : "v"(a), "v"(b), "v"(c)); return d;
}

// numpy pairwise sum of a[i]^2, n=256 (exact np order).
__device__ float np_sq_sum256(const float* __restrict__ a) {
    float tot[2];
    #pragma unroll 1
    for (int h = 0; h < 2; ++h) {
        const float* p = a + h * 128;
        float r[8];
        #pragma unroll
        for (int j = 0; j < 8; ++j) r[j] = fmul(p[j], p[j]);
        #pragma unroll 1
        for (int i = 8; i < 128; i += 8)
            #pragma unroll
            for (int j = 0; j < 8; ++j) r[j] = fadd(r[j], fmul(p[i + j], p[i + j]));
        tot[h] = fadd(fadd(fadd(r[0], r[1]), fadd(r[2], r[3])),
                      fadd(fadd(r[4], r[5]), fadd(r[6], r[7])));
    }
    return fadd(tot[0], tot[1]);
}

// ---- k_prep: fused {cvt 32-code swizzled tiles (128 blk), codestats (4), colsum (64)} ----
__global__ void k_prep(const float* __restrict__ cb, char* __restrict__ cbh,
                       float* __restrict__ scp, float* __restrict__ mAcc) {
    int bx = blockIdx.x;
    if (bx < 128) {
        int g = bx * 256 + threadIdx.x;          // 0..32767 f16x8 groups
        int t = g >> 10, c = (g >> 5) & 31, j = g & 31;
        const float* s = cb + (size_t)(t * 32 + c) * DDIM + j * 8;
        float4 v0 = *(const float4*)s, v1 = *(const float4*)(s + 4);
        f16x8 h;
        h[0] = (_Float16)(v0.x * 1024.f); h[1] = (_Float16)(v0.y * 1024.f);
        h[2] = (_Float16)(v0.z * 1024.f); h[3] = (_Float16)(v0.w * 1024.f);
        h[4] = (_Float16)(v1.x * 1024.f); h[5] = (_Float16)(v1.y * 1024.f);
        h[6] = (_Float16)(v1.z * 1024.f); h[7] = (_Float16)(v1.w * 1024.f);
        uint byte = (uint)(c * 512 + j * 16) ^ (uint)((c & 7) << 4);
        *(f16x8*)(cbh + (size_t)t * 16384 + byte) = h;
    } else if (bx < 132) {
        int code = (bx - 128) * 256 + threadIdx.x;
        if (code < KCODES) scp[code] = np_sq_sum256(cb + (size_t)code * DDIM);
    } else {
        int d = threadIdx.x;
        int b = bx - 132;                        // 64 blocks x 16 rows
        float s = 0.f;
        for (int i = 0; i < 16; ++i) s += cb[(size_t)(b * 16 + i) * DDIM + d];
        atomicAdd(&mAcc[d], s);
    }
}

// ---- k1c: finalize mean vector + ||m||^2 ----
__global__ void k_meanfin(const float* __restrict__ mAcc,
                          float* __restrict__ mvec, double* __restrict__ M2p) {
    __shared__ double red[256];
    int d = threadIdx.x;
    float m = mAcc[d] * (1.0f / 1024.0f);
    mvec[d] = m;
    red[d] = (double)m * (double)m;
    __syncthreads();
    for (int off = 128; off; off >>= 1) {
        if (d < off) red[d] += red[d + off];
        __syncthreads();
    }
    if (d == 0) *M2p = red[0];
}

#define GLOAD_LDS16(g, l) \
    __builtin_amdgcn_global_load_lds( \
        (const __attribute__((address_space(1))) void*)(g), \
        (__attribute__((address_space(3))) void*)(l), 16, 0, 0)

// ---- k2: main MFMA pass (256 thr, 128 rows, 32-code tiles) ----
__launch_bounds__(256)
__global__ void k_main(const float* __restrict__ z, const char* __restrict__ cbh,
                       const float* __restrict__ sc, const float* __restrict__ mvec,
                       float* __restrict__ out,
                       double* __restrict__ lossA, double* __restrict__ lossB) {
    __shared__ char tiles[2][16384] __attribute__((aligned(16)));
    __shared__ float sc_lds[1024];
    __shared__ float statA[128], statZM[128];
    __shared__ float lred[2];

    const int tid = threadIdx.x;
    const int wave = tid >> 6;          // 0..3
    const int lane = tid & 63;
    const int l15 = lane & 15;
    const int lg = lane >> 4;
    const int blockRow = blockIdx.x * 128;

    if (tid < 2) lred[tid] = 0.f;
    for (int i = tid; i < 1024; i += 256) sc_lds[i] = sc[i];

    // --- z rows -> fp16 A-frags; per-row sum(z^2), z.m (losses) ---
    f16x8 za[2][8];
    #pragma unroll
    for (int m = 0; m < 2; ++m) {
        const float* zr = z + (size_t)(blockRow + wave * 32 + m * 16 + l15) * DDIM;
        float a2 = 0.f, zm = 0.f;
        #pragma unroll
        for (int kk = 0; kk < 8; ++kk) {
            int d0 = kk * 32 + lg * 8;
            float4 v0 = *(const float4*)(zr + d0);
            float4 v1 = *(const float4*)(zr + d0 + 4);
            float4 w0 = *(const float4*)(mvec + d0);
            float4 w1 = *(const float4*)(mvec + d0 + 4);
            a2 += v0.x * v0.x + v0.y * v0.y + v0.z * v0.z + v0.w * v0.w;
            a2 += v1.x * v1.x + v1.y * v1.y + v1.z * v1.z + v1.w * v1.w;
            zm += v0.x * w0.x + v0.y * w0.y + v0.z * w0.z + v0.w * w0.w;
            zm += v1.x * w1.x + v1.y * w1.y + v1.z * w1.z + v1.w * w1.w;
            f16x8 h;
            h[0] = (_Float16)v0.x; h[1] = (_Float16)v0.y;
            h[2] = (_Float16)v0.z; h[3] = (_Float16)v0.w;
            h[4] = (_Float16)v1.x; h[5] = (_Float16)v1.y;
            h[6] = (_Float16)v1.z; h[7] = (_Float16)v1.w;
            za[m][kk] = h;
        }
        a2 += __shfl_xor(a2, 16); a2 += __shfl_xor(a2, 32);
        zm += __shfl_xor(zm, 16); zm += __shfl_xor(zm, 32);
        if (lg == 0) {
            statA[wave * 32 + m * 16 + l15] = a2;
            statZM[wave * 32 + m * 16 + l15] = zm;
        }
    }
    __syncthreads();   // drains all prior vm loads -> vmcnt bookkeeping exact

    float k1v[2][2][4], k2v[2][2][4], k3v[2][2][4];
    #pragma unroll
    for (int n = 0; n < 2; ++n)
        #pragma unroll
        for (int m = 0; m < 2; ++m)
            #pragma unroll
            for (int r = 0; r < 4; ++r) {
                k1v[n][m][r] = 3e38f; k2v[n][m][r] = 3e38f; k3v[n][m][r] = 3e38f;
            }

    // DMA stage: 4 x 16B per thread per tile (4 waves x 4KB = 16KB)
    const char* gsrc0 = cbh + (size_t)wave * 4096 + (size_t)lane * 16;
    #define STAGE(T, BUF) { \
        const char* g_ = gsrc0 + (size_t)(T) * 16384; \
        char* l_ = &tiles[BUF][wave * 4096]; \
        _Pragma("unroll") \
        for (int i_ = 0; i_ < 4; ++i_) GLOAD_LDS16(g_ + i_ * 1024, l_ + i_ * 1024); \
    }

    #define COMPUTE(T, BUF) { \
        f32x4v acc[2][2]; \
        _Pragma("unroll") \
        for (int m = 0; m < 2; ++m) \
            _Pragma("unroll") \
            for (int n = 0; n < 2; ++n) acc[m][n] = (f32x4v){0.f, 0.f, 0.f, 0.f}; \
        const char* tb = &tiles[BUF][0]; \
        _Pragma("unroll") \
        for (int kk = 0; kk < 8; ++kk) { \
            _Pragma("unroll") \
            for (int n = 0; n < 2; ++n) { \
                int lcode = n * 16 + l15; \
                uint byte = (uint)(lcode * 512 + kk * 64 + lg * 16) ^ (uint)((lcode & 7) << 4); \
                f16x8 b = *(const f16x8*)(tb + byte); \
                acc[0][n] = __builtin_amdgcn_mfma_f32_16x16x32_f16(za[0][kk], b, acc[0][n], 0, 0, 0); \
                acc[1][n] = __builtin_amdgcn_mfma_f32_16x16x32_f16(za[1][kk], b, acc[1][n], 0, 0, 0); \
            } \
        } \
        int tbase = (T) * 32; \
        _Pragma("unroll") \
        for (int n = 0; n < 2; ++n) { \
            int codev = tbase + n * 16 + l15; \
            float scv = sc_lds[codev]; \
            _Pragma("unroll") \
            for (int m = 0; m < 2; ++m) \
                _Pragma("unroll") \
                for (int r = 0; r < 4; ++r) { \
                    float s = fmaf(acc[m][n][r], -0.001953125f, scv); \
                    uint kb = (__float_as_uint(s) & 0xFFFFFC00u) | (uint)codev; \
                    float k = __uint_as_float(kb); \
                    float o1 = k1v[n][m][r], o2 = k2v[n][m][r]; \
                    k3v[n][m][r] = __builtin_amdgcn_fmed3f(o2, k3v[n][m][r], k); \
                    k2v[n][m][r] = __builtin_amdgcn_fmed3f(o1, o2, k); \
                    k1v[n][m][r] = fminf(o1, k); \
                } \
        } \
    }

    STAGE(0, 0);
    #pragma unroll 1
    for (int t = 0; t < 31; ++t) {
        STAGE(t + 1, (t + 1) & 1);
        asm volatile("s_waitcnt vmcnt(4)" ::: "memory");
        __builtin_amdgcn_s_barrier();
        __builtin_amdgcn_sched_barrier(0);
        COMPUTE(t, t & 1);
        __builtin_amdgcn_sched_barrier(0);
        __builtin_amdgcn_s_barrier();
    }
    asm volatile("s_waitcnt vmcnt(0)" ::: "memory");
    __builtin_amdgcn_s_barrier();
    __builtin_amdgcn_sched_barrier(0);
    COMPUTE(31, 1);

    // --- fold n=0/n=1 key banks, then cross-lane top-3 merge + encoded write ---
    float lA = 0.f, lB = 0.f;
    #pragma unroll
    for (int m = 0; m < 2; ++m)
        #pragma unroll
        for (int r = 0; r < 4; ++r) {
            float x1 = k1v[0][m][r], x2 = k2v[0][m][r], x3 = k3v[0][m][r];
            float y1 = k1v[1][m][r], y2 = k2v[1][m][r], y3 = k3v[1][m][r];
            float mx = fmaxf(x1, y1);
            float a3 = fminf(fminf(__builtin_amdgcn_fmed3f(x2, y2, mx), x3), y3);
            float a2 = fminf(fminf(mx, x2), y2);
            float a1 = fminf(x1, y1);
            #pragma unroll
            for (int mk = 1; mk <= 8; mk <<= 1) {
                float b1 = __shfl_xor(a1, mk);
                float b2 = __shfl_xor(a2, mk);
                float b3 = __shfl_xor(a3, mk);
                float mx2 = fmaxf(a1, b1);
                float n3 = fminf(fminf(__builtin_amdgcn_fmed3f(a2, b2, mx2), a3), b3);
                float n2 = fminf(fminf(mx2, a2), b2);
                a1 = fminf(a1, b1); a2 = n2; a3 = n3;
            }
            if (l15 == 0) {
                int rowL = wave * 32 + m * 16 + lg * 4 + r;
                int row = blockRow + rowL;
                int i1 = (int)(__float_as_uint(a1) & 1023u);
                int i2 = (int)(__float_as_uint(a2) & 1023u);
                int flag = (a3 - a1 < M1F) ? 2 : ((a2 - a1 < M1F) ? 1 : 0);
                int enc = (flag == 2) ? (i1 | (2 << 20))
                        : (flag == 1) ? (i1 | (i2 << 10) | (1 << 20))
                                      : i1;
                out[ND + 2 + (size_t)row] = (float)enc;   // exact (< 2^22)
                lA += statA[rowL] + a1;
                lB += statA[rowL] - 2.f * statZM[rowL];
            }
        }
    if (l15 == 0) { atomicAdd(&lred[0], lA); atomicAdd(&lred[1], lB); }
    __syncthreads();
    if (tid == 0) {
        atomicAdd(lossA, (double)lred[0]);
        atomicAdd(lossB, (double)lred[1]);
    }
}

// ---- k_tail: decode + refine (pair per-wave, full per-block) + gather ----
__launch_bounds__(256)
__global__ void k_tail(const float* __restrict__ z, const float* __restrict__ cb,
                       const float* __restrict__ scp, float* __restrict__ out) {
    __shared__ int idx[128];
    __shared__ uint pairList[128];
    __shared__ int fullList[128];
    __shared__ int cnts[2];
    __shared__ float PB[4][3][256];      // per-wave z,c1,c2 (12 KB)
    __shared__ float zrow[256];
    __shared__ float avs[256];
    __shared__ int ais[256];

    const int tid = threadIdx.x;
    const int wv = tid >> 6;
    const int lane = tid & 63;
    const int blockRow = blockIdx.x * 128;

    if (tid < 2) cnts[tid] = 0;
    __syncthreads();
    if (tid < 128) {
        int enc = (int)out[ND + 2 + (size_t)(blockRow + tid)];
        idx[tid] = enc & 1023;
        if (enc >= (1 << 20)) {
            if ((enc >> 20) == 1) {
                int p = atomicAdd(&cnts[0], 1);
                pairList[p] = (uint)tid | ((uint)(enc & 0xFFFFF) << 7);
            } else {
                int p = atomicAdd(&cnts[1], 1);
                fullList[p] = tid;
            }
        }
    }
    __syncthreads();
    int nPair = cnts[0], nFull = cnts[1];

    // --- pair refine: wave wv handles entries wv, wv+4, ... (np-exact) ---
    for (int e = wv; e < nPair; e += 4) {
        uint pe = pairList[e];
        int rowL = (int)(pe & 127u);
        int i1 = (int)((pe >> 7) & 1023u);
        int i2 = (int)((pe >> 17) & 1023u);
        int row = blockRow + rowL;
        *(float4*)&PB[wv][0][lane * 4] = *(const float4*)(z + (size_t)row * DDIM + lane * 4);
        *(float4*)&PB[wv][1][lane * 4] = *(const float4*)(cb + (size_t)i1 * DDIM + lane * 4);
        *(float4*)&PB[wv][2][lane * 4] = *(const float4*)(cb + (size_t)i2 * DDIM + lane * 4);
        asm volatile("s_waitcnt vmcnt(0) lgkmcnt(0)" ::: "memory");
        float A = np_sq_sum256(PB[wv][0]);
        float dA = 0.f, dB = 0.f;
        #pragma unroll 4
        for (int d4 = 0; d4 < 64; ++d4) {
            float4 zz = *(const float4*)&PB[wv][0][d4 * 4];
            float4 ca = *(const float4*)&PB[wv][1][d4 * 4];
            float4 cc = *(const float4*)&PB[wv][2][d4 * 4];
            dA = ffma(zz.x, ca.x, dA); dA = ffma(zz.y, ca.y, dA);
            dA = ffma(zz.z, ca.z, dA); dA = ffma(zz.w, ca.w, dA);
            dB = ffma(zz.x, cc.x, dB); dB = ffma(zz.y, cc.y, dB);
            dB = ffma(zz.z, cc.z, dB); dB = ffma(zz.w, cc.w, dB);
        }
        float d1 = fsub(fadd(A, scp[i1]), fmul(2.f, dA));
        float d2 = fsub(fadd(A, scp[i2]), fmul(2.f, dB));
        int win = (d2 < d1 || (d2 == d1 && i2 < i1)) ? i2 : i1;
        if (lane == 0) idx[rowL] = win;
    }
    __syncthreads();

    // --- full np rescan rows: whole block per row ---
    #pragma unroll 1
    for (int e = 0; e < nFull; ++e) {
        int rowL = fullList[e];
        int row = blockRow + rowL;
        __syncthreads();
        if (tid < 64)
            *(float4*)&zrow[tid * 4] = *(const float4*)(z + (size_t)row * DDIM + tid * 4);
        __syncthreads();
        float A = np_sq_sum256(zrow);
        float d0 = 0.f, d1 = 0.f, d2 = 0.f, d3 = 0.f;
        const float* c0 = cb + (size_t)(tid + 0) * DDIM;
        const float* c1 = cb + (size_t)(tid + 256) * DDIM;
        const float* c2 = cb + (size_t)(tid + 512) * DDIM;
        const float* c3 = cb + (size_t)(tid + 768) * DDIM;
        #pragma unroll 4
        for (int q = 0; q < 64; ++q) {
            float4 zz = *(const float4*)&zrow[q * 4];
            float4 a = *(const float4*)(c0 + q * 4);
            float4 b = *(const float4*)(c1 + q * 4);
            float4 c = *(const float4*)(c2 + q * 4);
            float4 d = *(const float4*)(c3 + q * 4);
            d0 = ffma(zz.x, a.x, d0); d0 = ffma(zz.y, a.y, d0);
            d0 = ffma(zz.z, a.z, d0); d0 = ffma(zz.w, a.w, d0);
            d1 = ffma(zz.x, b.x, d1); d1 = ffma(zz.y, b.y, d1);
            d1 = ffma(zz.z, b.z, d1); d1 = ffma(zz.w, b.w, d1);
            d2 = ffma(zz.x, c.x, d2); d2 = ffma(zz.y, c.y, d2);
            d2 = ffma(zz.z, c.z, d2); d2 = ffma(zz.w, c.w, d2);
            d3 = ffma(zz.x, d.x, d3); d3 = ffma(zz.y, d.y, d3);
            d3 = ffma(zz.z, d.z, d3); d3 = ffma(zz.w, d.w, d3);
        }
        float best = 1e30f; int bi = 0x7fffffff;
        float dd[4] = {d0, d1, d2, d3};
        #pragma unroll
        for (int kk = 0; kk < 4; ++kk) {
            int code = tid + kk * 256;
            float dist = fsub(fadd(A, scp[code]), fmul(2.f, dd[kk]));
            if (dist < best || (dist == best && code < bi)) { best = dist; bi = code; }
        }
        avs[tid] = best; ais[tid] = bi;
        __syncthreads();
        for (int off = 128; off; off >>= 1) {
            if (tid < off) {
                float o = avs[tid + off]; int oi = ais[tid + off];
                if (o < avs[tid] || (o == avs[tid] && oi < ais[tid])) {
                    avs[tid] = o; ais[tid] = oi;
                }
            }
            __syncthreads();
        }
        if (tid == 0) idx[rowL] = ais[0];
        __syncthreads();
    }
    __syncthreads();

    // --- finalize index slots + gather z_q ---
    if (tid < 128) out[ND + 2 + (size_t)(blockRow + tid)] = (float)idx[tid];
    float4* out4 = (float4*)out;
    const float4* cb4 = (const float4*)cb;
    #pragma unroll 4
    for (int i = 0; i < 32; ++i) {
        int q = i * 256 + tid;              // 128 rows x 64 float4
        int rowL = q >> 6, ch = q & 63;
        int code = idx[rowL];
        out4[(size_t)(blockRow + rowL) * 64 + ch] = cb4[(size_t)code * 64 + ch];
    }
}

// ---- k4: finalize scalar losses ----
__global__ void k_final(const double* __restrict__ lossA, const double* __restrict__ lossB,
                        const double* __restrict__ M2p, float* __restrict__ out) {
    if (threadIdx.x == 0) {
        double nd = (double)ND;
        out[ND] = (float)(*lossA / nd);
        out[ND + 1] = (float)((*lossB + (double)NROWS * (*M2p)) / nd);
    }
}

extern "C" void kernel_launch(void* const* d_in, const int* in_sizes, int n_in,
                              void* d_out, int out_size, void* d_ws, size_t ws_size,
                              hipStream_t stream) {
    const float* z = (const float*)d_in[0];
    const float* cb = (const float*)d_in[1];
    float* out = (float*)d_out;

    // ws: [0 lossA][8 lossB][16 M2p][32 mAcc 1KB][2048 mvec][4096 scp 4KB]
    //     [8192 cbh 512KB]
    double* lossA = (double*)d_ws;
    double* lossB = lossA + 1;
    double* M2p   = lossA + 2;
    float*  mAcc  = (float*)((char*)d_ws + 32);
    float*  mvec  = (float*)((char*)d_ws + 2048);
    float*  scp   = (float*)((char*)d_ws + 4096);
    char*   cbh   = (char*)d_ws + 8192;

    hipMemsetAsync(d_ws, 0, 1056, stream);
    k_prep<<<196, 256, 0, stream>>>(cb, cbh, scp, mAcc);
    k_meanfin<<<1, 256, 0, stream>>>(mAcc, mvec, M2p);
    k_main<<<NROWS / 128, 256, 0, stream>>>(z, cbh, scp, mvec, out, lossA, lossB);
    k_tail<<<NROWS / 128, 256, 0, stream>>>(z, cb, scp, out);
    k_final<<<1, 64, 0, stream>>>(lossA, lossB, M2p, out);
}